// Round 4
// baseline (1110.734 us; speedup 1.0000x reference)
//
#include <hip/hip_runtime.h>

#define N_NODES 100000
#define N_EDGES 1600000
#define IN_F 128
#define HID 64
#define NBUCK 1563          // ceil(100000 / 64), 64 nodes per bucket
#define NBPAD 2048

// ---------------- per-node degree (R2-proven) ----------------
__global__ __launch_bounds__(256) void k_zero_cnt(int* __restrict__ cnt) {
    int i = blockIdx.x * 256 + threadIdx.x;
    if (i < 100352) cnt[i] = 0;            // incl. padded tail so bucket sums see zeros
}

__global__ __launch_bounds__(256) void k_hist(const int* __restrict__ dst,
                                              int* __restrict__ cnt) {
    int e = blockIdx.x * 256 + threadIdx.x;
    if (e < N_EDGES) atomicAdd(&cnt[dst[e]], 1);
}

__global__ __launch_bounds__(256) void k_dinv(const int* __restrict__ cnt,
                                              float* __restrict__ dinv) {
    int i = blockIdx.x * 256 + threadIdx.x;
    if (i < N_NODES) dinv[i] = rsqrtf((float)(cnt[i] + 1));  // +1 self-loop
}

// ---------------- bucket counts: plain segment-sum of cnt (no atomics) ----------------
__global__ __launch_bounds__(256) void k_bsum(const int* __restrict__ cnt,
                                              int* __restrict__ bcnt) {
    int b = blockIdx.x * 256 + threadIdx.x;
    if (b >= NBPAD) return;
    int s = 0;
    if (b < NBUCK) {
        const int4* c4 = (const int4*)(cnt + b * 64);   // 256 B aligned
        #pragma unroll
        for (int q = 0; q < 16; ++q) {
            int4 v = c4[q];
            s += v.x + v.y + v.z + v.w;
        }
    }
    bcnt[b] = s;
}

// ---------------- single-block scan over 2048 bucket counts ----------------
__global__ __launch_bounds__(1024) void k_bscan(const int* __restrict__ bcnt,
                                                int* __restrict__ boff,
                                                int* __restrict__ bcur) {
    __shared__ int s[1024];
    const int t = threadIdx.x;
    int v0 = bcnt[2 * t], v1 = bcnt[2 * t + 1];
    int p = v0 + v1;
    s[t] = p;
    __syncthreads();
    for (int o = 1; o < 1024; o <<= 1) {
        int tt = (t >= o) ? s[t - o] : 0;
        __syncthreads();
        s[t] += tt;
        __syncthreads();
    }
    int base = s[t] - p;                    // exclusive prefix of pair
    boff[2 * t] = base;         bcur[2 * t] = base;
    boff[2 * t + 1] = base + v0; bcur[2 * t + 1] = base + v0;
}

// ---------------- bin: append packed (dst_local, src) records per bucket ----------------
__global__ __launch_bounds__(256) void k_bin(const int* __restrict__ src,
                                             const int* __restrict__ dst,
                                             int* __restrict__ bcur,
                                             int* __restrict__ bin) {
    int e = blockIdx.x * 256 + threadIdx.x;
    if (e >= N_EDGES) return;
    int s = src[e], d = dst[e];
    int slot = atomicAdd(&bcur[d >> 6], 1);
    bin[slot] = ((d & 63) << 17) | s;       // src < 2^17, dst_local < 2^6
}

// ---------------- layer 1 GEMM: h' = (x @ W1) * dinv (R2-proven) ----------------
__global__ __launch_bounds__(256) void k_gemm1(const float* __restrict__ x,
                                               const float* __restrict__ W1,
                                               const float* __restrict__ dinv,
                                               float* __restrict__ h) {
    __shared__ float Ws[IN_F * HID];   // 32 KB
    __shared__ float xs[16][IN_F];     // 8 KB
    for (int t = threadIdx.x; t < IN_F * HID; t += 256) Ws[t] = W1[t];
    const int wave = threadIdx.x >> 6, lane = threadIdx.x & 63;
    const int ngroups = N_NODES / 16;  // 6250, exact
    for (int g = blockIdx.x; g < ngroups; g += gridDim.x) {
        __syncthreads();               // covers Ws load on first iter
        for (int t = threadIdx.x; t < 16 * IN_F; t += 256)
            xs[t >> 7][t & 127] = x[(size_t)(g * 16 + (t >> 7)) * IN_F + (t & 127)];
        __syncthreads();
        const int n0 = g * 16 + wave * 4;
        float a0 = 0.f, a1 = 0.f, a2 = 0.f, a3 = 0.f;
        #pragma unroll 8
        for (int k = 0; k < IN_F; ++k) {
            float wv = Ws[k * HID + lane];
            a0 += xs[wave * 4 + 0][k] * wv;
            a1 += xs[wave * 4 + 1][k] * wv;
            a2 += xs[wave * 4 + 2][k] * wv;
            a3 += xs[wave * 4 + 3][k] * wv;
        }
        h[(size_t)(n0 + 0) * HID + lane] = a0 * dinv[n0 + 0];
        h[(size_t)(n0 + 1) * HID + lane] = a1 * dinv[n0 + 1];
        h[(size_t)(n0 + 2) * HID + lane] = a2 * dinv[n0 + 2];
        h[(size_t)(n0 + 3) * HID + lane] = a3 * dinv[n0 + 3];
    }
}

// ---------------- layer 1: bucket gather via LDS atomics + ReLU + GEMM2 fused ----------------
// block per bucket (64 nodes). acc[dl][f] += h1[src][f]; order-insensitive.
__global__ __launch_bounds__(256) void k_gather1(const float* __restrict__ h1,
                                                 const int* __restrict__ bin,
                                                 const int* __restrict__ boff,
                                                 const float* __restrict__ dinv,
                                                 const float* __restrict__ b1,
                                                 const float* __restrict__ W2,
                                                 float2* __restrict__ h2p) {
    __shared__ float acc[64][64];      // 16 KB; lane=f -> 2 lanes/bank, conflict-free
    const int b = blockIdx.x;
    const int tid = threadIdx.x, wave = tid >> 6, lane = tid & 63;
    // init with self-loop term h1'[node]
    #pragma unroll
    for (int it = 0; it < 16; ++it) {
        int idx = it * 256 + tid;      // [0, 4096)
        int dl = idx >> 6, f = idx & 63;
        int gnode = b * 64 + dl;
        float v = 0.f;
        if (gnode < N_NODES) v = h1[(size_t)gnode * HID + f];
        acc[dl][f] = v;
    }
    __syncthreads();
    const int beg = boff[b], end = boff[b + 1];
    for (int base = beg + wave * 64; base < end; base += 256) {
        const int cnt = min(64, end - base);
        int entry = (lane < cnt) ? bin[base + lane] : 0;
        if (cnt == 64) {
            #pragma unroll 8
            for (int j = 0; j < 64; ++j) {
                int v = __shfl(entry, j, 64);
                atomicAdd(&acc[(v >> 17) & 63][lane], h1[(size_t)(v & 0x1FFFF) * HID + lane]);
            }
        } else {
            for (int j = 0; j < cnt; ++j) {
                int v = __shfl(entry, j, 64);
                atomicAdd(&acc[(v >> 17) & 63][lane], h1[(size_t)(v & 0x1FFFF) * HID + lane]);
            }
        }
    }
    __syncthreads();
    // epilogue: y = relu(dinv*acc + b1); h2p = dinv * (y @ W2)
    for (int dl = wave; dl < 64; dl += 4) {
        int gnode = b * 64 + dl;
        if (gnode >= N_NODES) break;   // only bucket 1562's tail
        float y = dinv[gnode] * acc[dl][lane] + b1[lane];
        y = fmaxf(y, 0.f);
        float c0 = y * W2[lane * 2 + 0];
        float c1 = y * W2[lane * 2 + 1];
        #pragma unroll
        for (int o = 32; o > 0; o >>= 1) {
            c0 += __shfl_xor(c0, o, 64);
            c1 += __shfl_xor(c1, o, 64);
        }
        if (lane == 0) {
            float di = dinv[gnode];
            h2p[gnode] = make_float2(c0 * di, c1 * di);
        }
    }
}

// ---------------- layer 2: bucket gather via LDS atomics + finalize ----------------
__global__ __launch_bounds__(256) void k_gather2(const float2* __restrict__ h2p,
                                                 const int* __restrict__ bin,
                                                 const int* __restrict__ boff,
                                                 const float* __restrict__ dinv,
                                                 const float* __restrict__ b2,
                                                 float* __restrict__ out) {
    __shared__ float acc2[64][2];
    const int b = blockIdx.x;
    const int tid = threadIdx.x;
    if (tid < 128) {
        int dl = tid >> 1, c = tid & 1;
        int gnode = b * 64 + dl;
        float v = 0.f;
        if (gnode < N_NODES) v = ((const float*)h2p)[gnode * 2 + c];  // self-loop term
        acc2[dl][c] = v;
    }
    __syncthreads();
    const int beg = boff[b], end = boff[b + 1];
    for (int i = beg + tid; i < end; i += 256) {
        int v = bin[i];
        float2 hv = h2p[v & 0x1FFFF];
        int dl = (v >> 17) & 63;
        atomicAdd(&acc2[dl][0], hv.x);
        atomicAdd(&acc2[dl][1], hv.y);
    }
    __syncthreads();
    if (tid < 128) {
        int dl = tid >> 1, c = tid & 1;
        int gnode = b * 64 + dl;
        if (gnode < N_NODES)
            out[gnode * 2 + c] = dinv[gnode] * acc2[dl][c] + b2[c];
    }
}

extern "C" void kernel_launch(void* const* d_in, const int* in_sizes, int n_in,
                              void* d_out, int out_size, void* d_ws, size_t ws_size,
                              hipStream_t stream) {
    const float* x  = (const float*)d_in[0];
    const int*   ei = (const int*)d_in[1];
    const float* W1 = (const float*)d_in[2];
    const float* b1 = (const float*)d_in[3];
    const float* W2 = (const float*)d_in[4];
    const float* b2 = (const float*)d_in[5];
    float* out = (float*)d_out;

    const int* src = ei;
    const int* dst = ei + N_EDGES;

    // workspace layout (4 B units; all offsets 256-int aligned, no aliasing)
    int*    wsi  = (int*)d_ws;
    int*    cnt  = wsi;                        // [0, 100352)
    float*  dinv = (float*)(wsi + 100352);     // [100352, 200704)
    int*    bcnt = wsi + 200704;               // [200704, 202752)
    int*    boff = wsi + 202752;               // [202752, 204800)
    int*    bcur = wsi + 204800;               // [204800, 206848)
    int*    bin  = wsi + 206848;               // [206848, 1806848)
    float*  h1p  = (float*)(wsi + 1806848);    // [1806848, 8206848)
    float2* h2p  = (float2*)(wsi + 8206848);   // [8206848, 8406848)

    dim3 B(256);
    k_zero_cnt<<<392, B, 0, stream>>>(cnt);
    k_hist    <<<(N_EDGES + 255) / 256, B, 0, stream>>>(dst, cnt);
    k_dinv    <<<(N_NODES + 255) / 256, B, 0, stream>>>(cnt, dinv);
    k_bsum    <<<(NBPAD + 255) / 256, B, 0, stream>>>(cnt, bcnt);
    k_bscan   <<<1, 1024, 0, stream>>>(bcnt, boff, bcur);
    k_bin     <<<(N_EDGES + 255) / 256, B, 0, stream>>>(src, dst, bcur, bin);

    k_gemm1   <<<1024, B, 0, stream>>>(x, W1, dinv, h1p);
    k_gather1 <<<NBUCK, B, 0, stream>>>(h1p, bin, boff, dinv, b1, W2, h2p);
    k_gather2 <<<NBUCK, B, 0, stream>>>(h2p, bin, boff, dinv, b2, out);
}

// Round 5
// 587.415 us; speedup vs baseline: 1.8909x; 1.8909x over previous
//
#include <hip/hip_runtime.h>

#define N_NODES 100000
#define N_EDGES 1600000
#define IN_F 128
#define HID 64
#define NBUCK 1563          // ceil(100000 / 64), 64 nodes per bucket

// ---------------- per-node degree (R2-proven) ----------------
__global__ __launch_bounds__(256) void k_zero_cnt(int* __restrict__ cnt) {
    int i = blockIdx.x * 256 + threadIdx.x;
    if (i < 100352) cnt[i] = 0;
}

__global__ __launch_bounds__(256) void k_hist(const int* __restrict__ dst,
                                              int* __restrict__ cnt) {
    int e = blockIdx.x * 256 + threadIdx.x;
    if (e < N_EDGES) atomicAdd(&cnt[dst[e]], 1);
}

__global__ __launch_bounds__(256) void k_dinv(const int* __restrict__ cnt,
                                              float* __restrict__ dinv) {
    int i = blockIdx.x * 256 + threadIdx.x;
    if (i < N_NODES) dinv[i] = rsqrtf((float)(cnt[i] + 1));  // +1 self-loop
}

// ---------------- global scan of per-node counts (R2-proven) ----------------
__global__ __launch_bounds__(256) void k_scan_block(const int* __restrict__ cnt,
                                                    int* __restrict__ loc,
                                                    int* __restrict__ bsum) {
    __shared__ int s[256];
    int i = blockIdx.x * 256 + threadIdx.x;
    int v = (i < N_NODES) ? cnt[i] : 0;
    s[threadIdx.x] = v;
    __syncthreads();
    for (int o = 1; o < 256; o <<= 1) {
        int t = (threadIdx.x >= o) ? s[threadIdx.x - o] : 0;
        __syncthreads();
        s[threadIdx.x] += t;
        __syncthreads();
    }
    if (i < N_NODES) loc[i] = s[threadIdx.x];
    if (threadIdx.x == 255) bsum[blockIdx.x] = s[255];
}

__global__ __launch_bounds__(512) void k_scan_top(const int* __restrict__ bsum,
                                                  int* __restrict__ boffT, int nb) {
    __shared__ int s[512];
    int v = (threadIdx.x < nb) ? bsum[threadIdx.x] : 0;
    s[threadIdx.x] = v;
    __syncthreads();
    for (int o = 1; o < 512; o <<= 1) {
        int t = (threadIdx.x >= o) ? s[threadIdx.x - o] : 0;
        __syncthreads();
        s[threadIdx.x] += t;
        __syncthreads();
    }
    if (threadIdx.x < nb) boffT[threadIdx.x] = s[threadIdx.x] - v;
}

__global__ __launch_bounds__(256) void k_scan_fin(const int* __restrict__ cnt,
                                                  const int* __restrict__ loc,
                                                  const int* __restrict__ boffT,
                                                  int* __restrict__ off) {
    int i = blockIdx.x * 256 + threadIdx.x;
    if (i < N_NODES)
        off[i] = loc[i] - cnt[i] + boffT[blockIdx.x];  // exclusive global prefix
    if (i == 0) off[N_NODES] = N_EDGES;
}

// bucket append cursors: node order == bucket order, so bucket base = off[64b]
__global__ __launch_bounds__(256) void k_bcur(const int* __restrict__ off,
                                              int* __restrict__ bcur) {
    int b = blockIdx.x * 256 + threadIdx.x;
    if (b < NBUCK) bcur[b] = off[b * 64];
}

// ---------------- bin: append packed (dst_local, src) per bucket (R4-proven) ----------------
__global__ __launch_bounds__(256) void k_bin(const int* __restrict__ src,
                                             const int* __restrict__ dst,
                                             int* __restrict__ bcur,
                                             int* __restrict__ bin) {
    int e = blockIdx.x * 256 + threadIdx.x;
    if (e >= N_EDGES) return;
    int s = src[e], d = dst[e];
    int slot = atomicAdd(&bcur[d >> 6], 1);
    bin[slot] = ((d & 63) << 17) | s;       // src < 2^17, dst_local < 2^6
}

// ---------------- reorder2: bucket-grouped bin -> per-node CSR (writes stay in 4 KB window) --
__global__ __launch_bounds__(256) void k_reorder2(const int* __restrict__ bin,
                                                  const int* __restrict__ off,
                                                  int* __restrict__ csr) {
    __shared__ int cur[64];
    const int b = blockIdx.x;
    if (threadIdx.x < 64) cur[threadIdx.x] = off[b * 64 + threadIdx.x];  // alloc-safe read
    __syncthreads();
    const int beg = off[b * 64];
    const int end = off[min((b + 1) * 64, N_NODES)];
    for (int i = beg + threadIdx.x; i < end; i += 256) {
        int v = bin[i];
        int slot = atomicAdd(&cur[(v >> 17) & 63], 1);   // ds_atomic_rtn, no shfl mixing
        csr[slot] = v & 0x1FFFF;
    }
}

// ---------------- layer 1 GEMM: h' = (x @ W1) * dinv (R2-proven) ----------------
__global__ __launch_bounds__(256) void k_gemm1(const float* __restrict__ x,
                                               const float* __restrict__ W1,
                                               const float* __restrict__ dinv,
                                               float* __restrict__ h) {
    __shared__ float Ws[IN_F * HID];   // 32 KB
    __shared__ float xs[16][IN_F];     // 8 KB
    for (int t = threadIdx.x; t < IN_F * HID; t += 256) Ws[t] = W1[t];
    const int wave = threadIdx.x >> 6, lane = threadIdx.x & 63;
    const int ngroups = N_NODES / 16;  // 6250, exact
    for (int g = blockIdx.x; g < ngroups; g += gridDim.x) {
        __syncthreads();               // covers Ws load on first iter
        for (int t = threadIdx.x; t < 16 * IN_F; t += 256)
            xs[t >> 7][t & 127] = x[(size_t)(g * 16 + (t >> 7)) * IN_F + (t & 127)];
        __syncthreads();
        const int n0 = g * 16 + wave * 4;
        float a0 = 0.f, a1 = 0.f, a2 = 0.f, a3 = 0.f;
        #pragma unroll 8
        for (int k = 0; k < IN_F; ++k) {
            float wv = Ws[k * HID + lane];
            a0 += xs[wave * 4 + 0][k] * wv;
            a1 += xs[wave * 4 + 1][k] * wv;
            a2 += xs[wave * 4 + 2][k] * wv;
            a3 += xs[wave * 4 + 3][k] * wv;
        }
        h[(size_t)(n0 + 0) * HID + lane] = a0 * dinv[n0 + 0];
        h[(size_t)(n0 + 1) * HID + lane] = a1 * dinv[n0 + 1];
        h[(size_t)(n0 + 2) * HID + lane] = a2 * dinv[n0 + 2];
        h[(size_t)(n0 + 3) * HID + lane] = a3 * dinv[n0 + 3];
    }
}

// ---------------- layer 1 gather + ReLU + GEMM2 fused (R2-proven) ----------------
__global__ __launch_bounds__(256) void k_gather1(const float* __restrict__ h1,
                                                 const int* __restrict__ off,
                                                 const int* __restrict__ csr,
                                                 const float* __restrict__ dinv,
                                                 const float* __restrict__ b1,
                                                 const float* __restrict__ W2,
                                                 float2* __restrict__ h2p) {
    const int wave = threadIdx.x >> 6, lane = threadIdx.x & 63;
    const int d = blockIdx.x * 4 + wave;   // grid = 25000 blocks, exact
    const int beg = off[d], end = off[d + 1];
    float acc = h1[(size_t)d * HID + lane];           // self-loop term
    for (int base = beg; base < end; base += 64) {
        const int cnt = min(64, end - base);
        int sidx = (lane < cnt) ? csr[base + lane] : 0;
        for (int j = 0; j < cnt; ++j) {
            int s = __shfl(sidx, j, 64);
            acc += h1[(size_t)s * HID + lane];
        }
    }
    float y = dinv[d] * acc + b1[lane];
    y = y > 0.f ? y : 0.f;
    float c0 = y * W2[lane * 2 + 0];
    float c1 = y * W2[lane * 2 + 1];
    #pragma unroll
    for (int o = 32; o > 0; o >>= 1) {
        c0 += __shfl_xor(c0, o, 64);
        c1 += __shfl_xor(c1, o, 64);
    }
    if (lane == 0) {
        float di = dinv[d];
        h2p[d] = make_float2(c0 * di, c1 * di);
    }
}

// ---------------- layer 2 gather + finalize (R2-proven) ----------------
__global__ __launch_bounds__(256) void k_gather2(const float2* __restrict__ h2p,
                                                 const int* __restrict__ off,
                                                 const int* __restrict__ csr,
                                                 const float* __restrict__ dinv,
                                                 const float* __restrict__ b2,
                                                 float* __restrict__ out) {
    int i = blockIdx.x * 256 + threadIdx.x;
    if (i >= N_NODES) return;
    int beg = off[i], end = off[i + 1];
    float2 a = h2p[i];                                // self-loop term
    for (int s = beg; s < end; ++s) {
        float2 v = h2p[csr[s]];
        a.x += v.x;
        a.y += v.y;
    }
    float di = dinv[i];
    out[i * 2 + 0] = di * a.x + b2[0];
    out[i * 2 + 1] = di * a.y + b2[1];
}

extern "C" void kernel_launch(void* const* d_in, const int* in_sizes, int n_in,
                              void* d_out, int out_size, void* d_ws, size_t ws_size,
                              hipStream_t stream) {
    const float* x  = (const float*)d_in[0];
    const int*   ei = (const int*)d_in[1];
    const float* W1 = (const float*)d_in[2];
    const float* b1 = (const float*)d_in[3];
    const float* W2 = (const float*)d_in[4];
    const float* b2 = (const float*)d_in[5];
    float* out = (float*)d_out;

    const int* src = ei;
    const int* dst = ei + N_EDGES;

    // workspace layout (4 B units; no aliasing; total ~40.8 MB, R1 proved >52 MB available)
    int*    wsi   = (int*)d_ws;
    int*    cnt   = wsi;                        // [0, 100352)
    int*    off   = wsi + 100352;               // [100352, 200704)  (N+1 used)
    int*    loc   = wsi + 200704;               // [200704, 301056)
    int*    bsum  = wsi + 301056;               // 512
    int*    boffT = wsi + 301568;               // 512
    int*    bcur  = wsi + 302080;               // 2048
    float*  dinv  = (float*)(wsi + 304128);     // 100352
    int*    bin   = wsi + 404480;               // 1600000
    int*    csr   = wsi + 2004480;              // 1600000
    float*  h1p   = (float*)(wsi + 3604480);    // 6400000
    float2* h2p   = (float2*)(wsi + 10004480);  // 100000 float2

    const int NB = (N_NODES + 255) / 256;       // 391
    dim3 B(256);
    k_zero_cnt  <<<392, B, 0, stream>>>(cnt);
    k_hist      <<<(N_EDGES + 255) / 256, B, 0, stream>>>(dst, cnt);
    k_dinv      <<<NB, B, 0, stream>>>(cnt, dinv);
    k_scan_block<<<NB, B, 0, stream>>>(cnt, loc, bsum);
    k_scan_top  <<<1, 512, 0, stream>>>(bsum, boffT, NB);
    k_scan_fin  <<<NB, B, 0, stream>>>(cnt, loc, boffT, off);
    k_bcur      <<<(NBUCK + 255) / 256, B, 0, stream>>>(off, bcur);
    k_bin       <<<(N_EDGES + 255) / 256, B, 0, stream>>>(src, dst, bcur, bin);
    k_reorder2  <<<NBUCK, B, 0, stream>>>(bin, off, csr);

    k_gemm1     <<<1024, B, 0, stream>>>(x, W1, dinv, h1p);
    k_gather1   <<<N_NODES / 4, B, 0, stream>>>(h1p, off, csr, dinv, b1, W2, h2p);
    k_gather2   <<<NB, B, 0, stream>>>(h2p, off, csr, dinv, b2, out);
}

// Round 6
// 494.882 us; speedup vs baseline: 2.2444x; 1.1870x over previous
//
#include <hip/hip_runtime.h>

#define N_NODES 100000
#define N_EDGES 1600000
#define IN_F 128
#define HID 64
#define NBUCK 1563          // ceil(100000 / 64), 64 nodes per bucket
#define NSHARD 32           // cursor shards per bucket; const mod 8 -> XCD-aligned tails

// ---------------- zero cnt + scnt (contiguous) ----------------
__global__ __launch_bounds__(256) void k_zero(int* __restrict__ p) {
    int i = blockIdx.x * 256 + threadIdx.x;
    if (i < 150528) p[i] = 0;              // cnt[100352] + scnt[50176]
}

// ---------------- per-node degree + sharded bucket histogram (fused) ----------------
__global__ __launch_bounds__(256) void k_hist(const int* __restrict__ dst,
                                              int* __restrict__ cnt,
                                              int* __restrict__ scnt) {
    int e = blockIdx.x * 256 + threadIdx.x;
    if (e >= N_EDGES) return;
    int d = dst[e];
    atomicAdd(&cnt[d], 1);                                  // depth ~16
    atomicAdd(&scnt[((d >> 6) << 5) + (blockIdx.x & 31)], 1); // depth ~32
}

__global__ __launch_bounds__(256) void k_dinv(const int* __restrict__ cnt,
                                              float* __restrict__ dinv) {
    int i = blockIdx.x * 256 + threadIdx.x;
    if (i < N_NODES) dinv[i] = rsqrtf((float)(cnt[i] + 1));  // +1 self-loop
}

// ---------------- global scan of per-node counts (R2-proven) ----------------
__global__ __launch_bounds__(256) void k_scan_block(const int* __restrict__ cnt,
                                                    int* __restrict__ loc,
                                                    int* __restrict__ bsum) {
    __shared__ int s[256];
    int i = blockIdx.x * 256 + threadIdx.x;
    int v = (i < N_NODES) ? cnt[i] : 0;
    s[threadIdx.x] = v;
    __syncthreads();
    for (int o = 1; o < 256; o <<= 1) {
        int t = (threadIdx.x >= o) ? s[threadIdx.x - o] : 0;
        __syncthreads();
        s[threadIdx.x] += t;
        __syncthreads();
    }
    if (i < N_NODES) loc[i] = s[threadIdx.x];
    if (threadIdx.x == 255) bsum[blockIdx.x] = s[255];
}

__global__ __launch_bounds__(512) void k_scan_top(const int* __restrict__ bsum,
                                                  int* __restrict__ boffT, int nb) {
    __shared__ int s[512];
    int v = (threadIdx.x < nb) ? bsum[threadIdx.x] : 0;
    s[threadIdx.x] = v;
    __syncthreads();
    for (int o = 1; o < 512; o <<= 1) {
        int t = (threadIdx.x >= o) ? s[threadIdx.x - o] : 0;
        __syncthreads();
        s[threadIdx.x] += t;
        __syncthreads();
    }
    if (threadIdx.x < nb) boffT[threadIdx.x] = s[threadIdx.x] - v;
}

__global__ __launch_bounds__(256) void k_scan_fin(const int* __restrict__ cnt,
                                                  const int* __restrict__ loc,
                                                  const int* __restrict__ boffT,
                                                  int* __restrict__ off) {
    int i = blockIdx.x * 256 + threadIdx.x;
    if (i < N_NODES)
        off[i] = loc[i] - cnt[i] + boffT[blockIdx.x];  // exclusive global prefix
    if (i == 0) off[N_NODES] = N_EDGES;
}

// ---------------- shard cursors: lay 32 shards contiguously inside bucket window ----------
__global__ __launch_bounds__(256) void k_scur(const int* __restrict__ off,
                                              const int* __restrict__ scnt,
                                              int* __restrict__ scur) {
    int b = blockIdx.x * 256 + threadIdx.x;
    if (b >= NBUCK) return;
    int base = off[b * 64];                // bucket window start (b*64 <= 99968 < N)
    #pragma unroll
    for (int s = 0; s < NSHARD; ++s) {
        scur[(b << 5) + s] = base;
        base += scnt[(b << 5) + s];        // sums to next bucket's start by construction
    }
}

// ---------------- bin: append packed (dst_local, src) via sharded cursors ----------------
// grid/block mapping MUST match k_hist (it does: same 6250x256 e-mapping)
__global__ __launch_bounds__(256) void k_bin(const int* __restrict__ src,
                                             const int* __restrict__ dst,
                                             int* __restrict__ scur,
                                             int* __restrict__ bin) {
    int e = blockIdx.x * 256 + threadIdx.x;
    if (e >= N_EDGES) return;
    int s = src[e], d = dst[e];
    int slot = atomicAdd(&scur[((d >> 6) << 5) + (blockIdx.x & 31)], 1);
    bin[slot] = ((d & 63) << 17) | s;      // src < 2^17, dst_local < 2^6
}

// ---------------- reorder2: bucket-grouped bin -> per-node CSR (R5-proven) ----------------
__global__ __launch_bounds__(256) void k_reorder2(const int* __restrict__ bin,
                                                  const int* __restrict__ off,
                                                  int* __restrict__ csr) {
    __shared__ int cur[64];
    const int b = blockIdx.x;
    if (threadIdx.x < 64) cur[threadIdx.x] = off[b * 64 + threadIdx.x];
    __syncthreads();
    const int beg = off[b * 64];
    const int end = off[min((b + 1) * 64, N_NODES)];
    for (int i = beg + threadIdx.x; i < end; i += 256) {
        int v = bin[i];
        int slot = atomicAdd(&cur[(v >> 17) & 63], 1);
        csr[slot] = v & 0x1FFFF;
    }
}

// ---------------- layer 1 GEMM: h' = (x @ W1) * dinv (R2-proven) ----------------
__global__ __launch_bounds__(256) void k_gemm1(const float* __restrict__ x,
                                               const float* __restrict__ W1,
                                               const float* __restrict__ dinv,
                                               float* __restrict__ h) {
    __shared__ float Ws[IN_F * HID];   // 32 KB
    __shared__ float xs[16][IN_F];     // 8 KB
    for (int t = threadIdx.x; t < IN_F * HID; t += 256) Ws[t] = W1[t];
    const int wave = threadIdx.x >> 6, lane = threadIdx.x & 63;
    const int ngroups = N_NODES / 16;  // 6250, exact
    for (int g = blockIdx.x; g < ngroups; g += gridDim.x) {
        __syncthreads();               // covers Ws load on first iter
        for (int t = threadIdx.x; t < 16 * IN_F; t += 256)
            xs[t >> 7][t & 127] = x[(size_t)(g * 16 + (t >> 7)) * IN_F + (t & 127)];
        __syncthreads();
        const int n0 = g * 16 + wave * 4;
        float a0 = 0.f, a1 = 0.f, a2 = 0.f, a3 = 0.f;
        #pragma unroll 8
        for (int k = 0; k < IN_F; ++k) {
            float wv = Ws[k * HID + lane];
            a0 += xs[wave * 4 + 0][k] * wv;
            a1 += xs[wave * 4 + 1][k] * wv;
            a2 += xs[wave * 4 + 2][k] * wv;
            a3 += xs[wave * 4 + 3][k] * wv;
        }
        h[(size_t)(n0 + 0) * HID + lane] = a0 * dinv[n0 + 0];
        h[(size_t)(n0 + 1) * HID + lane] = a1 * dinv[n0 + 1];
        h[(size_t)(n0 + 2) * HID + lane] = a2 * dinv[n0 + 2];
        h[(size_t)(n0 + 3) * HID + lane] = a3 * dinv[n0 + 3];
    }
}

// ---------------- layer 1 gather + ReLU + GEMM2 fused (R2-proven) ----------------
__global__ __launch_bounds__(256) void k_gather1(const float* __restrict__ h1,
                                                 const int* __restrict__ off,
                                                 const int* __restrict__ csr,
                                                 const float* __restrict__ dinv,
                                                 const float* __restrict__ b1,
                                                 const float* __restrict__ W2,
                                                 float2* __restrict__ h2p) {
    const int wave = threadIdx.x >> 6, lane = threadIdx.x & 63;
    const int d = blockIdx.x * 4 + wave;   // grid = 25000 blocks, exact
    const int beg = off[d], end = off[d + 1];
    float acc = h1[(size_t)d * HID + lane];           // self-loop term
    for (int base = beg; base < end; base += 64) {
        const int cnt = min(64, end - base);
        int sidx = (lane < cnt) ? csr[base + lane] : 0;
        for (int j = 0; j < cnt; ++j) {
            int s = __shfl(sidx, j, 64);
            acc += h1[(size_t)s * HID + lane];
        }
    }
    float y = dinv[d] * acc + b1[lane];
    y = y > 0.f ? y : 0.f;
    float c0 = y * W2[lane * 2 + 0];
    float c1 = y * W2[lane * 2 + 1];
    #pragma unroll
    for (int o = 32; o > 0; o >>= 1) {
        c0 += __shfl_xor(c0, o, 64);
        c1 += __shfl_xor(c1, o, 64);
    }
    if (lane == 0) {
        float di = dinv[d];
        h2p[d] = make_float2(c0 * di, c1 * di);
    }
}

// ---------------- layer 2 gather + finalize (R2-proven) ----------------
__global__ __launch_bounds__(256) void k_gather2(const float2* __restrict__ h2p,
                                                 const int* __restrict__ off,
                                                 const int* __restrict__ csr,
                                                 const float* __restrict__ dinv,
                                                 const float* __restrict__ b2,
                                                 float* __restrict__ out) {
    int i = blockIdx.x * 256 + threadIdx.x;
    if (i >= N_NODES) return;
    int beg = off[i], end = off[i + 1];
    float2 a = h2p[i];                                // self-loop term
    for (int s = beg; s < end; ++s) {
        float2 v = h2p[csr[s]];
        a.x += v.x;
        a.y += v.y;
    }
    float di = dinv[i];
    out[i * 2 + 0] = di * a.x + b2[0];
    out[i * 2 + 1] = di * a.y + b2[1];
}

extern "C" void kernel_launch(void* const* d_in, const int* in_sizes, int n_in,
                              void* d_out, int out_size, void* d_ws, size_t ws_size,
                              hipStream_t stream) {
    const float* x  = (const float*)d_in[0];
    const int*   ei = (const int*)d_in[1];
    const float* W1 = (const float*)d_in[2];
    const float* b1 = (const float*)d_in[3];
    const float* W2 = (const float*)d_in[4];
    const float* b2 = (const float*)d_in[5];
    float* out = (float*)d_out;

    const int* src = ei;
    const int* dst = ei + N_EDGES;

    // workspace layout (4 B units; no aliasing; ~41.2 MB)
    int*    wsi   = (int*)d_ws;
    int*    cnt   = wsi;                        // 100352
    int*    scnt  = wsi + 100352;               // 50176 (NBUCK*32 = 50016 used)
    int*    off   = wsi + 150528;               // 100352 (N+1 used)
    int*    loc   = wsi + 250880;               // 100352
    int*    bsum  = wsi + 351232;               // 512
    int*    boffT = wsi + 351744;               // 512
    int*    scur  = wsi + 352256;               // 50176
    float*  dinv  = (float*)(wsi + 402432);     // 100352
    int*    bin   = wsi + 502784;               // 1600000
    int*    csr   = wsi + 2102784;              // 1600000
    float*  h1p   = (float*)(wsi + 3702784);    // 6400000
    float2* h2p   = (float2*)(wsi + 10102784);  // 100000 float2

    const int NB = (N_NODES + 255) / 256;       // 391
    const int EB = (N_EDGES + 255) / 256;       // 6250
    dim3 B(256);
    k_zero      <<<588, B, 0, stream>>>(cnt);   // cnt + scnt contiguous
    k_hist      <<<EB, B, 0, stream>>>(dst, cnt, scnt);
    k_dinv      <<<NB, B, 0, stream>>>(cnt, dinv);
    k_scan_block<<<NB, B, 0, stream>>>(cnt, loc, bsum);
    k_scan_top  <<<1, 512, 0, stream>>>(bsum, boffT, NB);
    k_scan_fin  <<<NB, B, 0, stream>>>(cnt, loc, boffT, off);
    k_scur      <<<(NBUCK + 255) / 256, B, 0, stream>>>(off, scnt, scur);
    k_bin       <<<EB, B, 0, stream>>>(src, dst, scur, bin);
    k_reorder2  <<<NBUCK, B, 0, stream>>>(bin, off, csr);

    k_gemm1     <<<1024, B, 0, stream>>>(x, W1, dinv, h1p);
    k_gather1   <<<N_NODES / 4, B, 0, stream>>>(h1p, off, csr, dinv, b1, W2, h2p);
    k_gather2   <<<NB, B, 0, stream>>>(h2p, off, csr, dinv, b2, out);
}

// Round 7
// 361.224 us; speedup vs baseline: 3.0749x; 1.3700x over previous
//
#include <hip/hip_runtime.h>

#define N_NODES 100000
#define N_EDGES 1600000
#define IN_F 128
#define HID 64
#define NBUCK 1563          // ceil(100000 / 64), 64 nodes per bucket
#define NBP 1600            // padded bucket stride (shard-major scnt)
#define NSHARD 32
#define GS 256              // grid-stride blocks for hist_s / bin (mapping must match!)

// ---------------- zero scnt ----------------
__global__ __launch_bounds__(256) void k_zero(int* __restrict__ scnt) {
    int i = blockIdx.x * 256 + threadIdx.x;
    if (i < NSHARD * NBP) scnt[i] = 0;
}

// ---------------- sharded bucket histogram, LDS-aggregated ----------------
// scnt layout: [shard][NBP] (shard-major -> contiguous coalesced flush)
__global__ __launch_bounds__(256) void k_hist_s(const int* __restrict__ dst,
                                                int* __restrict__ scnt) {
    __shared__ int h[NBP];
    for (int t = threadIdx.x; t < NBP; t += 256) h[t] = 0;
    __syncthreads();
    const int g = blockIdx.x;
    for (int e = g * 256 + threadIdx.x; e < N_EDGES; e += GS * 256)
        atomicAdd(&h[dst[e] >> 6], 1);
    __syncthreads();
    int* base = scnt + (g & 31) * NBP;
    for (int t = threadIdx.x; t < NBUCK; t += 256) {
        int v = h[t];
        if (v) atomicAdd(&base[t], v);      // depth 8 (256 blocks / 32 shards)
    }
}

// ---------------- bucket totals ----------------
__global__ __launch_bounds__(256) void k_bsum(const int* __restrict__ scnt,
                                              int* __restrict__ bt) {
    int b = blockIdx.x * 256 + threadIdx.x;
    if (b >= 2048) return;
    int s = 0;
    if (b < NBUCK) {
        #pragma unroll
        for (int sh = 0; sh < NSHARD; ++sh) s += scnt[sh * NBP + b];
    }
    bt[b] = s;
}

// ---------------- single-block exclusive scan over 2048 bucket totals ----------------
__global__ __launch_bounds__(1024) void k_bscan(const int* __restrict__ bt,
                                                int* __restrict__ bbase,
                                                int* __restrict__ off) {
    __shared__ int s[1024];
    const int t = threadIdx.x;
    int v0 = bt[2 * t], v1 = bt[2 * t + 1];
    int p = v0 + v1;
    s[t] = p;
    __syncthreads();
    for (int o = 1; o < 1024; o <<= 1) {
        int tt = (t >= o) ? s[t - o] : 0;
        __syncthreads();
        s[t] += tt;
        __syncthreads();
    }
    int base = s[t] - p;
    bbase[2 * t] = base;
    bbase[2 * t + 1] = base + v0;
    if (t == 0) off[N_NODES] = N_EDGES;     // CSR sentinel
}

// ---------------- shard cursors laid contiguously inside each bucket window ----------------
__global__ __launch_bounds__(256) void k_scur(const int* __restrict__ bbase,
                                              const int* __restrict__ scnt,
                                              int* __restrict__ scur) {
    int b = blockIdx.x * 256 + threadIdx.x;
    if (b >= NBUCK) return;
    int base = bbase[b];
    #pragma unroll
    for (int s = 0; s < NSHARD; ++s) {
        scur[(b << 5) + s] = base;
        base += scnt[s * NBP + b];
    }
}

// ---------------- bin: append packed (dst_local, src); mapping matches k_hist_s ----------
__global__ __launch_bounds__(256) void k_bin(const int* __restrict__ src,
                                             const int* __restrict__ dst,
                                             int* __restrict__ scur,
                                             int* __restrict__ bin) {
    const int g = blockIdx.x;
    for (int e = g * 256 + threadIdx.x; e < N_EDGES; e += GS * 256) {
        int s = src[e], d = dst[e];
        int slot = atomicAdd(&scur[((d >> 6) << 5) + (g & 31)], 1);
        bin[slot] = ((d & 63) << 17) | s;   // src < 2^17, dst_local < 2^6
    }
}

// ---------------- per-bucket: histogram -> off/dinv, then reorder bin -> csr ----------------
// conservative construction: LDS atomics only, serial t0 scan, syncthreads between phases
__global__ __launch_bounds__(256) void k_csr(const int* __restrict__ bin,
                                             const int* __restrict__ bbase,
                                             int* __restrict__ off,
                                             float* __restrict__ dinv,
                                             int* __restrict__ csr) {
    __shared__ int cnt64[64];
    __shared__ int cur64[64];
    const int b = blockIdx.x;
    if (threadIdx.x < 64) cnt64[threadIdx.x] = 0;
    __syncthreads();
    const int beg = bbase[b], end = bbase[b + 1];
    for (int i = beg + threadIdx.x; i < end; i += 256)
        atomicAdd(&cnt64[(bin[i] >> 17) & 63], 1);
    __syncthreads();
    if (threadIdx.x == 0) {                 // serial exclusive scan (64 iters, negligible)
        int run = beg;
        #pragma unroll
        for (int j = 0; j < 64; ++j) {
            cur64[j] = run;
            run += cnt64[j];
        }
    }
    __syncthreads();
    if (threadIdx.x < 64) {
        int node = b * 64 + threadIdx.x;
        if (node < N_NODES) {
            off[node] = cur64[threadIdx.x];
            dinv[node] = rsqrtf((float)(cnt64[threadIdx.x] + 1));  // +1 self-loop
        }
    }
    __syncthreads();
    for (int i = beg + threadIdx.x; i < end; i += 256) {
        int v = bin[i];
        int slot = atomicAdd(&cur64[(v >> 17) & 63], 1);
        csr[slot] = v & 0x1FFFF;
    }
}

// ---------------- layer 1 GEMM: h' = (x @ W1) * dinv (R2-proven) ----------------
__global__ __launch_bounds__(256) void k_gemm1(const float* __restrict__ x,
                                               const float* __restrict__ W1,
                                               const float* __restrict__ dinv,
                                               float* __restrict__ h) {
    __shared__ float Ws[IN_F * HID];   // 32 KB
    __shared__ float xs[16][IN_F];     // 8 KB
    for (int t = threadIdx.x; t < IN_F * HID; t += 256) Ws[t] = W1[t];
    const int wave = threadIdx.x >> 6, lane = threadIdx.x & 63;
    const int ngroups = N_NODES / 16;  // 6250, exact
    for (int g = blockIdx.x; g < ngroups; g += gridDim.x) {
        __syncthreads();               // covers Ws load on first iter
        for (int t = threadIdx.x; t < 16 * IN_F; t += 256)
            xs[t >> 7][t & 127] = x[(size_t)(g * 16 + (t >> 7)) * IN_F + (t & 127)];
        __syncthreads();
        const int n0 = g * 16 + wave * 4;
        float a0 = 0.f, a1 = 0.f, a2 = 0.f, a3 = 0.f;
        #pragma unroll 8
        for (int k = 0; k < IN_F; ++k) {
            float wv = Ws[k * HID + lane];
            a0 += xs[wave * 4 + 0][k] * wv;
            a1 += xs[wave * 4 + 1][k] * wv;
            a2 += xs[wave * 4 + 2][k] * wv;
            a3 += xs[wave * 4 + 3][k] * wv;
        }
        h[(size_t)(n0 + 0) * HID + lane] = a0 * dinv[n0 + 0];
        h[(size_t)(n0 + 1) * HID + lane] = a1 * dinv[n0 + 1];
        h[(size_t)(n0 + 2) * HID + lane] = a2 * dinv[n0 + 2];
        h[(size_t)(n0 + 3) * HID + lane] = a3 * dinv[n0 + 3];
    }
}

// ---------------- layer 1 gather + ReLU + GEMM2 fused (R2-proven) ----------------
__global__ __launch_bounds__(256) void k_gather1(const float* __restrict__ h1,
                                                 const int* __restrict__ off,
                                                 const int* __restrict__ csr,
                                                 const float* __restrict__ dinv,
                                                 const float* __restrict__ b1,
                                                 const float* __restrict__ W2,
                                                 float2* __restrict__ h2p) {
    const int wave = threadIdx.x >> 6, lane = threadIdx.x & 63;
    const int d = blockIdx.x * 4 + wave;   // grid = 25000 blocks, exact
    const int beg = off[d], end = off[d + 1];
    float acc = h1[(size_t)d * HID + lane];           // self-loop term
    for (int base = beg; base < end; base += 64) {
        const int cnt = min(64, end - base);
        int sidx = (lane < cnt) ? csr[base + lane] : 0;
        for (int j = 0; j < cnt; ++j) {
            int s = __shfl(sidx, j, 64);
            acc += h1[(size_t)s * HID + lane];
        }
    }
    float y = dinv[d] * acc + b1[lane];
    y = y > 0.f ? y : 0.f;
    float c0 = y * W2[lane * 2 + 0];
    float c1 = y * W2[lane * 2 + 1];
    #pragma unroll
    for (int o = 32; o > 0; o >>= 1) {
        c0 += __shfl_xor(c0, o, 64);
        c1 += __shfl_xor(c1, o, 64);
    }
    if (lane == 0) {
        float di = dinv[d];
        h2p[d] = make_float2(c0 * di, c1 * di);
    }
}

// ---------------- layer 2 gather + finalize (R2-proven) ----------------
__global__ __launch_bounds__(256) void k_gather2(const float2* __restrict__ h2p,
                                                 const int* __restrict__ off,
                                                 const int* __restrict__ csr,
                                                 const float* __restrict__ dinv,
                                                 const float* __restrict__ b2,
                                                 float* __restrict__ out) {
    int i = blockIdx.x * 256 + threadIdx.x;
    if (i >= N_NODES) return;
    int beg = off[i], end = off[i + 1];
    float2 a = h2p[i];                                // self-loop term
    for (int s = beg; s < end; ++s) {
        float2 v = h2p[csr[s]];
        a.x += v.x;
        a.y += v.y;
    }
    float di = dinv[i];
    out[i * 2 + 0] = di * a.x + b2[0];
    out[i * 2 + 1] = di * a.y + b2[1];
}

extern "C" void kernel_launch(void* const* d_in, const int* in_sizes, int n_in,
                              void* d_out, int out_size, void* d_ws, size_t ws_size,
                              hipStream_t stream) {
    const float* x  = (const float*)d_in[0];
    const int*   ei = (const int*)d_in[1];
    const float* W1 = (const float*)d_in[2];
    const float* b1 = (const float*)d_in[3];
    const float* W2 = (const float*)d_in[4];
    const float* b2 = (const float*)d_in[5];
    float* out = (float*)d_out;

    const int* src = ei;
    const int* dst = ei + N_EDGES;

    // workspace layout (4 B units; no aliasing)
    int*    wsi   = (int*)d_ws;
    int*    scnt  = wsi;                        // 51200 (32 x 1600)
    int*    bt    = wsi + 51200;                // 2048
    int*    bbase = wsi + 53248;                // 2048
    int*    scur  = wsi + 55296;                // 50176
    int*    off   = wsi + 105472;               // 100352 (N+1 used)
    float*  dinv  = (float*)(wsi + 205824);     // 100352
    int*    bin   = wsi + 306176;               // 1600000
    int*    csr   = wsi + 1906176;              // 1600000
    float*  h1p   = (float*)(wsi + 3506176);    // 6400000
    float2* h2p   = (float2*)(wsi + 9906176);   // 100000 float2

    dim3 B(256);
    k_zero   <<<(NSHARD * NBP + 255) / 256, B, 0, stream>>>(scnt);
    k_hist_s <<<GS, B, 0, stream>>>(dst, scnt);
    k_bsum   <<<8, B, 0, stream>>>(scnt, bt);
    k_bscan  <<<1, 1024, 0, stream>>>(bt, bbase, off);
    k_scur   <<<(NBUCK + 255) / 256, B, 0, stream>>>(bbase, scnt, scur);
    k_bin    <<<GS, B, 0, stream>>>(src, dst, scur, bin);
    k_csr    <<<NBUCK, B, 0, stream>>>(bin, bbase, off, dinv, csr);

    k_gemm1  <<<1024, B, 0, stream>>>(x, W1, dinv, h1p);
    k_gather1<<<N_NODES / 4, B, 0, stream>>>(h1p, off, csr, dinv, b1, W2, h2p);
    k_gather2<<<(N_NODES + 255) / 256, B, 0, stream>>>(h2p, off, csr, dinv, b2, out);
}

// Round 8
// 355.605 us; speedup vs baseline: 3.1235x; 1.0158x over previous
//
#include <hip/hip_runtime.h>
#include <hip/hip_fp16.h>

#define N_NODES 100000
#define N_EDGES 1600000
#define IN_F 128
#define HID 64
#define NBUCK 1563          // ceil(100000 / 64), 64 nodes per bucket
#define NBP 1600            // padded bucket stride (shard-major scnt)
#define NSHARD 32
#define GS 256              // grid-stride blocks for hist_s / bin (mapping must match!)

// ---------------- zero scnt ----------------
__global__ __launch_bounds__(256) void k_zero(int* __restrict__ scnt) {
    int i = blockIdx.x * 256 + threadIdx.x;
    if (i < NSHARD * NBP) scnt[i] = 0;
}

// ---------------- sharded bucket histogram, LDS-aggregated (R7-proven) ----------------
__global__ __launch_bounds__(256) void k_hist_s(const int* __restrict__ dst,
                                                int* __restrict__ scnt) {
    __shared__ int h[NBP];
    for (int t = threadIdx.x; t < NBP; t += 256) h[t] = 0;
    __syncthreads();
    const int g = blockIdx.x;
    for (int e = g * 256 + threadIdx.x; e < N_EDGES; e += GS * 256)
        atomicAdd(&h[dst[e] >> 6], 1);
    __syncthreads();
    int* base = scnt + (g & 31) * NBP;
    for (int t = threadIdx.x; t < NBUCK; t += 256) {
        int v = h[t];
        if (v) atomicAdd(&base[t], v);      // depth 8 (256 blocks / 32 shards)
    }
}

// ---------------- bucket totals ----------------
__global__ __launch_bounds__(256) void k_bsum(const int* __restrict__ scnt,
                                              int* __restrict__ bt) {
    int b = blockIdx.x * 256 + threadIdx.x;
    if (b >= 2048) return;
    int s = 0;
    if (b < NBUCK) {
        #pragma unroll
        for (int sh = 0; sh < NSHARD; ++sh) s += scnt[sh * NBP + b];
    }
    bt[b] = s;
}

// ---------------- single-block exclusive scan over 2048 bucket totals ----------------
__global__ __launch_bounds__(1024) void k_bscan(const int* __restrict__ bt,
                                                int* __restrict__ bbase,
                                                int* __restrict__ off) {
    __shared__ int s[1024];
    const int t = threadIdx.x;
    int v0 = bt[2 * t], v1 = bt[2 * t + 1];
    int p = v0 + v1;
    s[t] = p;
    __syncthreads();
    for (int o = 1; o < 1024; o <<= 1) {
        int tt = (t >= o) ? s[t - o] : 0;
        __syncthreads();
        s[t] += tt;
        __syncthreads();
    }
    int base = s[t] - p;
    bbase[2 * t] = base;
    bbase[2 * t + 1] = base + v0;
    if (t == 0) off[N_NODES] = N_EDGES;     // CSR sentinel
}

// ---------------- shard cursors laid contiguously inside each bucket window ----------------
__global__ __launch_bounds__(256) void k_scur(const int* __restrict__ bbase,
                                              const int* __restrict__ scnt,
                                              int* __restrict__ scur) {
    int b = blockIdx.x * 256 + threadIdx.x;
    if (b >= NBUCK) return;
    int base = bbase[b];
    #pragma unroll
    for (int s = 0; s < NSHARD; ++s) {
        scur[(b << 5) + s] = base;
        base += scnt[s * NBP + b];
    }
}

// ---------------- bin: append packed (dst_local, src); mapping matches k_hist_s ----------
__global__ __launch_bounds__(256) void k_bin(const int* __restrict__ src,
                                             const int* __restrict__ dst,
                                             int* __restrict__ scur,
                                             int* __restrict__ bin) {
    const int g = blockIdx.x;
    for (int e = g * 256 + threadIdx.x; e < N_EDGES; e += GS * 256) {
        int s = src[e], d = dst[e];
        int slot = atomicAdd(&scur[((d >> 6) << 5) + (g & 31)], 1);
        bin[slot] = ((d & 63) << 17) | s;   // src < 2^17, dst_local < 2^6
    }
}

// ---------------- per-bucket: histogram -> off/dinv, then reorder bin -> csr (R7-proven) ----
__global__ __launch_bounds__(256) void k_csr(const int* __restrict__ bin,
                                             const int* __restrict__ bbase,
                                             int* __restrict__ off,
                                             float* __restrict__ dinv,
                                             int* __restrict__ csr) {
    __shared__ int cnt64[64];
    __shared__ int cur64[64];
    const int b = blockIdx.x;
    if (threadIdx.x < 64) cnt64[threadIdx.x] = 0;
    __syncthreads();
    const int beg = bbase[b], end = bbase[b + 1];
    for (int i = beg + threadIdx.x; i < end; i += 256)
        atomicAdd(&cnt64[(bin[i] >> 17) & 63], 1);
    __syncthreads();
    if (threadIdx.x == 0) {
        int run = beg;
        #pragma unroll
        for (int j = 0; j < 64; ++j) {
            cur64[j] = run;
            run += cnt64[j];
        }
    }
    __syncthreads();
    if (threadIdx.x < 64) {
        int node = b * 64 + threadIdx.x;
        if (node < N_NODES) {
            off[node] = cur64[threadIdx.x];
            dinv[node] = rsqrtf((float)(cnt64[threadIdx.x] + 1));  // +1 self-loop
        }
    }
    __syncthreads();
    for (int i = beg + threadIdx.x; i < end; i += 256) {
        int v = bin[i];
        int slot = atomicAdd(&cur64[(v >> 17) & 63], 1);
        csr[slot] = v & 0x1FFFF;
    }
}

// ---------------- layer 1 GEMM: h' = (x @ W1) * dinv -> fp16 ----------------
__global__ __launch_bounds__(256) void k_gemm1(const float* __restrict__ x,
                                               const float* __restrict__ W1,
                                               const float* __restrict__ dinv,
                                               __half* __restrict__ h) {
    __shared__ float Ws[IN_F * HID];   // 32 KB
    __shared__ float xs[16][IN_F];     // 8 KB
    for (int t = threadIdx.x; t < IN_F * HID; t += 256) Ws[t] = W1[t];
    const int wave = threadIdx.x >> 6, lane = threadIdx.x & 63;
    const int ngroups = N_NODES / 16;  // 6250, exact
    for (int g = blockIdx.x; g < ngroups; g += gridDim.x) {
        __syncthreads();               // covers Ws load on first iter
        for (int t = threadIdx.x; t < 16 * IN_F; t += 256)
            xs[t >> 7][t & 127] = x[(size_t)(g * 16 + (t >> 7)) * IN_F + (t & 127)];
        __syncthreads();
        const int n0 = g * 16 + wave * 4;
        float a0 = 0.f, a1 = 0.f, a2 = 0.f, a3 = 0.f;
        #pragma unroll 8
        for (int k = 0; k < IN_F; ++k) {
            float wv = Ws[k * HID + lane];
            a0 += xs[wave * 4 + 0][k] * wv;
            a1 += xs[wave * 4 + 1][k] * wv;
            a2 += xs[wave * 4 + 2][k] * wv;
            a3 += xs[wave * 4 + 3][k] * wv;
        }
        h[(size_t)(n0 + 0) * HID + lane] = __float2half(a0 * dinv[n0 + 0]);
        h[(size_t)(n0 + 1) * HID + lane] = __float2half(a1 * dinv[n0 + 1]);
        h[(size_t)(n0 + 2) * HID + lane] = __float2half(a2 * dinv[n0 + 2]);
        h[(size_t)(n0 + 3) * HID + lane] = __float2half(a3 * dinv[n0 + 3]);
    }
}

// ---------------- layer 1 gather + ReLU + GEMM2 fused (fp16 h1) ----------------
__global__ __launch_bounds__(256) void k_gather1(const __half* __restrict__ h1,
                                                 const int* __restrict__ off,
                                                 const int* __restrict__ csr,
                                                 const float* __restrict__ dinv,
                                                 const float* __restrict__ b1,
                                                 const float* __restrict__ W2,
                                                 float2* __restrict__ h2p) {
    const int wave = threadIdx.x >> 6, lane = threadIdx.x & 63;
    const int d = blockIdx.x * 4 + wave;   // grid = 25000 blocks, exact
    const int beg = off[d], end = off[d + 1];
    float acc = __half2float(h1[(size_t)d * HID + lane]);   // self-loop term
    for (int base = beg; base < end; base += 64) {
        const int cnt = min(64, end - base);
        int sidx = (lane < cnt) ? csr[base + lane] : 0;
        for (int j = 0; j < cnt; ++j) {
            int s = __shfl(sidx, j, 64);
            acc += __half2float(h1[(size_t)s * HID + lane]);
        }
    }
    float y = dinv[d] * acc + b1[lane];
    y = y > 0.f ? y : 0.f;
    float c0 = y * W2[lane * 2 + 0];
    float c1 = y * W2[lane * 2 + 1];
    #pragma unroll
    for (int o = 32; o > 0; o >>= 1) {
        c0 += __shfl_xor(c0, o, 64);
        c1 += __shfl_xor(c1, o, 64);
    }
    if (lane == 0) {
        float di = dinv[d];
        h2p[d] = make_float2(c0 * di, c1 * di);
    }
}

// ---------------- layer 2 gather + finalize (R2-proven) ----------------
__global__ __launch_bounds__(256) void k_gather2(const float2* __restrict__ h2p,
                                                 const int* __restrict__ off,
                                                 const int* __restrict__ csr,
                                                 const float* __restrict__ dinv,
                                                 const float* __restrict__ b2,
                                                 float* __restrict__ out) {
    int i = blockIdx.x * 256 + threadIdx.x;
    if (i >= N_NODES) return;
    int beg = off[i], end = off[i + 1];
    float2 a = h2p[i];                                // self-loop term
    for (int s = beg; s < end; ++s) {
        float2 v = h2p[csr[s]];
        a.x += v.x;
        a.y += v.y;
    }
    float di = dinv[i];
    out[i * 2 + 0] = di * a.x + b2[0];
    out[i * 2 + 1] = di * a.y + b2[1];
}

extern "C" void kernel_launch(void* const* d_in, const int* in_sizes, int n_in,
                              void* d_out, int out_size, void* d_ws, size_t ws_size,
                              hipStream_t stream) {
    const float* x  = (const float*)d_in[0];
    const int*   ei = (const int*)d_in[1];
    const float* W1 = (const float*)d_in[2];
    const float* b1 = (const float*)d_in[3];
    const float* W2 = (const float*)d_in[4];
    const float* b2 = (const float*)d_in[5];
    float* out = (float*)d_out;

    const int* src = ei;
    const int* dst = ei + N_EDGES;

    // workspace layout (4 B units; no aliasing)
    int*    wsi   = (int*)d_ws;
    int*    scnt  = wsi;                        // 51200 (32 x 1600)
    int*    bt    = wsi + 51200;                // 2048
    int*    bbase = wsi + 53248;                // 2048
    int*    scur  = wsi + 55296;                // 50176
    int*    off   = wsi + 105472;               // 100352 (N+1 used)
    float*  dinv  = (float*)(wsi + 205824);     // 100352
    int*    bin   = wsi + 306176;               // 1600000
    int*    csr   = wsi + 1906176;              // 1600000
    __half* h1p   = (__half*)(wsi + 3506176);   // 6.4M halves = 3.2M ints
    float2* h2p   = (float2*)(wsi + 6706176);   // 100000 float2

    dim3 B(256);
    k_zero   <<<(NSHARD * NBP + 255) / 256, B, 0, stream>>>(scnt);
    k_hist_s <<<GS, B, 0, stream>>>(dst, scnt);
    k_bsum   <<<8, B, 0, stream>>>(scnt, bt);
    k_bscan  <<<1, 1024, 0, stream>>>(bt, bbase, off);
    k_scur   <<<(NBUCK + 255) / 256, B, 0, stream>>>(bbase, scnt, scur);
    k_bin    <<<GS, B, 0, stream>>>(src, dst, scur, bin);
    k_csr    <<<NBUCK, B, 0, stream>>>(bin, bbase, off, dinv, csr);

    k_gemm1  <<<1024, B, 0, stream>>>(x, W1, dinv, h1p);
    k_gather1<<<N_NODES / 4, B, 0, stream>>>(h1p, off, csr, dinv, b1, W2, h2p);
    k_gather2<<<(N_NODES + 255) / 256, B, 0, stream>>>(h2p, off, csr, dinv, b2, out);
}

// Round 9
// 300.992 us; speedup vs baseline: 3.6902x; 1.1814x over previous
//
#include <hip/hip_runtime.h>
#include <hip/hip_fp16.h>

#define N_NODES 100000
#define N_EDGES 1600000
#define IN_F 128
#define HID 64
#define NBUCK 1563          // ceil(100000 / 64), 64 nodes per bucket
#define NBP 1600            // padded bucket stride (shard-major scnt)
#define NSHARD 32
#define GS 256              // grid-stride blocks for hist_s / bin (mapping must match!)

// ---------------- zero scnt ----------------
__global__ __launch_bounds__(256) void k_zero(int* __restrict__ scnt) {
    int i = blockIdx.x * 256 + threadIdx.x;
    if (i < NSHARD * NBP) scnt[i] = 0;
}

// ---------------- sharded bucket histogram, LDS-aggregated (R7-proven) ----------------
__global__ __launch_bounds__(256) void k_hist_s(const int* __restrict__ dst,
                                                int* __restrict__ scnt) {
    __shared__ int h[NBP];
    for (int t = threadIdx.x; t < NBP; t += 256) h[t] = 0;
    __syncthreads();
    const int g = blockIdx.x;
    for (int e = g * 256 + threadIdx.x; e < N_EDGES; e += GS * 256)
        atomicAdd(&h[dst[e] >> 6], 1);
    __syncthreads();
    int* base = scnt + (g & 31) * NBP;
    for (int t = threadIdx.x; t < NBUCK; t += 256) {
        int v = h[t];
        if (v) atomicAdd(&base[t], v);      // depth 8 (256 blocks / 32 shards)
    }
}

// ---------------- bucket totals ----------------
__global__ __launch_bounds__(256) void k_bsum(const int* __restrict__ scnt,
                                              int* __restrict__ bt) {
    int b = blockIdx.x * 256 + threadIdx.x;
    if (b >= 2048) return;
    int s = 0;
    if (b < NBUCK) {
        #pragma unroll
        for (int sh = 0; sh < NSHARD; ++sh) s += scnt[sh * NBP + b];
    }
    bt[b] = s;
}

// ---------------- single-block exclusive scan over 2048 bucket totals ----------------
__global__ __launch_bounds__(1024) void k_bscan(const int* __restrict__ bt,
                                                int* __restrict__ bbase,
                                                int* __restrict__ off) {
    __shared__ int s[1024];
    const int t = threadIdx.x;
    int v0 = bt[2 * t], v1 = bt[2 * t + 1];
    int p = v0 + v1;
    s[t] = p;
    __syncthreads();
    for (int o = 1; o < 1024; o <<= 1) {
        int tt = (t >= o) ? s[t - o] : 0;
        __syncthreads();
        s[t] += tt;
        __syncthreads();
    }
    int base = s[t] - p;
    bbase[2 * t] = base;
    bbase[2 * t + 1] = base + v0;
    if (t == 0) off[N_NODES] = N_EDGES;     // CSR sentinel
}

// ---------------- shard cursors laid contiguously inside each bucket window ----------------
__global__ __launch_bounds__(256) void k_scur(const int* __restrict__ bbase,
                                              const int* __restrict__ scnt,
                                              int* __restrict__ scur) {
    int b = blockIdx.x * 256 + threadIdx.x;
    if (b >= NBUCK) return;
    int base = bbase[b];
    #pragma unroll
    for (int s = 0; s < NSHARD; ++s) {
        scur[(b << 5) + s] = base;
        base += scnt[s * NBP + b];
    }
}

// ---------------- bin: append packed (dst_local, src); mapping matches k_hist_s ----------
__global__ __launch_bounds__(256) void k_bin(const int* __restrict__ src,
                                             const int* __restrict__ dst,
                                             int* __restrict__ scur,
                                             int* __restrict__ bin) {
    const int g = blockIdx.x;
    for (int e = g * 256 + threadIdx.x; e < N_EDGES; e += GS * 256) {
        int s = src[e], d = dst[e];
        int slot = atomicAdd(&scur[((d >> 6) << 5) + (g & 31)], 1);
        bin[slot] = ((d & 63) << 17) | s;   // src < 2^17, dst_local < 2^6
    }
}

// ---------------- per-bucket: histogram -> off/dinv, then reorder bin -> csr (R7-proven) ----
__global__ __launch_bounds__(256) void k_csr(const int* __restrict__ bin,
                                             const int* __restrict__ bbase,
                                             int* __restrict__ off,
                                             float* __restrict__ dinv,
                                             int* __restrict__ csr) {
    __shared__ int cnt64[64];
    __shared__ int cur64[64];
    const int b = blockIdx.x;
    if (threadIdx.x < 64) cnt64[threadIdx.x] = 0;
    __syncthreads();
    const int beg = bbase[b], end = bbase[b + 1];
    for (int i = beg + threadIdx.x; i < end; i += 256)
        atomicAdd(&cnt64[(bin[i] >> 17) & 63], 1);
    __syncthreads();
    if (threadIdx.x == 0) {
        int run = beg;
        #pragma unroll
        for (int j = 0; j < 64; ++j) {
            cur64[j] = run;
            run += cnt64[j];
        }
    }
    __syncthreads();
    if (threadIdx.x < 64) {
        int node = b * 64 + threadIdx.x;
        if (node < N_NODES) {
            off[node] = cur64[threadIdx.x];
            dinv[node] = rsqrtf((float)(cnt64[threadIdx.x] + 1));  // +1 self-loop
        }
    }
    __syncthreads();
    for (int i = beg + threadIdx.x; i < end; i += 256) {
        int v = bin[i];
        int slot = atomicAdd(&cur64[(v >> 17) & 63], 1);
        csr[slot] = v & 0x1FFFF;
    }
}

// ---------------- layer 1 GEMM: h' = (x @ W1) * dinv -> fp16 (R8-proven) ----------------
__global__ __launch_bounds__(256) void k_gemm1(const float* __restrict__ x,
                                               const float* __restrict__ W1,
                                               const float* __restrict__ dinv,
                                               __half* __restrict__ h) {
    __shared__ float Ws[IN_F * HID];   // 32 KB
    __shared__ float xs[16][IN_F];     // 8 KB
    for (int t = threadIdx.x; t < IN_F * HID; t += 256) Ws[t] = W1[t];
    const int wave = threadIdx.x >> 6, lane = threadIdx.x & 63;
    const int ngroups = N_NODES / 16;  // 6250, exact
    for (int g = blockIdx.x; g < ngroups; g += gridDim.x) {
        __syncthreads();               // covers Ws load on first iter
        for (int t = threadIdx.x; t < 16 * IN_F; t += 256)
            xs[t >> 7][t & 127] = x[(size_t)(g * 16 + (t >> 7)) * IN_F + (t & 127)];
        __syncthreads();
        const int n0 = g * 16 + wave * 4;
        float a0 = 0.f, a1 = 0.f, a2 = 0.f, a3 = 0.f;
        #pragma unroll 8
        for (int k = 0; k < IN_F; ++k) {
            float wv = Ws[k * HID + lane];
            a0 += xs[wave * 4 + 0][k] * wv;
            a1 += xs[wave * 4 + 1][k] * wv;
            a2 += xs[wave * 4 + 2][k] * wv;
            a3 += xs[wave * 4 + 3][k] * wv;
        }
        h[(size_t)(n0 + 0) * HID + lane] = __float2half(a0 * dinv[n0 + 0]);
        h[(size_t)(n0 + 1) * HID + lane] = __float2half(a1 * dinv[n0 + 1]);
        h[(size_t)(n0 + 2) * HID + lane] = __float2half(a2 * dinv[n0 + 2]);
        h[(size_t)(n0 + 3) * HID + lane] = __float2half(a3 * dinv[n0 + 3]);
    }
}

// ---------------- layer 1 gather + ReLU + GEMM2 fused; 8 loads in flight ----------------
__global__ __launch_bounds__(256) void k_gather1(const __half* __restrict__ h1,
                                                 const int* __restrict__ off,
                                                 const int* __restrict__ csr,
                                                 const float* __restrict__ dinv,
                                                 const float* __restrict__ b1,
                                                 const float* __restrict__ W2,
                                                 float2* __restrict__ h2p) {
    const int wave = threadIdx.x >> 6, lane = threadIdx.x & 63;
    const int d = blockIdx.x * 4 + wave;   // grid = 25000 blocks, exact
    const int beg = off[d], end = off[d + 1];
    float acc = __half2float(h1[(size_t)d * HID + lane]);   // self-loop term
    for (int base = beg; base < end; base += 64) {
        const int cnt = min(64, end - base);
        int sidx = (lane < cnt) ? csr[base + lane] : 0;     // OOB lanes -> row 0 (safe)
        for (int j = 0; j < cnt; j += 8) {
            float v[8];
            #pragma unroll
            for (int u = 0; u < 8; ++u) {                   // 8 independent loads in flight
                int jj = j + u;
                int s = __shfl(sidx, jj & 63, 64);
                float t = __half2float(h1[(size_t)s * HID + lane]);
                v[u] = (jj < cnt) ? t : 0.f;
            }
            #pragma unroll
            for (int u = 0; u < 8; ++u) acc += v[u];
        }
    }
    float y = dinv[d] * acc + b1[lane];
    y = y > 0.f ? y : 0.f;
    float c0 = y * W2[lane * 2 + 0];
    float c1 = y * W2[lane * 2 + 1];
    #pragma unroll
    for (int o = 32; o > 0; o >>= 1) {
        c0 += __shfl_xor(c0, o, 64);
        c1 += __shfl_xor(c1, o, 64);
    }
    if (lane == 0) {
        float di = dinv[d];
        h2p[d] = make_float2(c0 * di, c1 * di);
    }
}

// ---------------- layer 2 gather + finalize (R2-proven) ----------------
__global__ __launch_bounds__(256) void k_gather2(const float2* __restrict__ h2p,
                                                 const int* __restrict__ off,
                                                 const int* __restrict__ csr,
                                                 const float* __restrict__ dinv,
                                                 const float* __restrict__ b2,
                                                 float* __restrict__ out) {
    int i = blockIdx.x * 256 + threadIdx.x;
    if (i >= N_NODES) return;
    int beg = off[i], end = off[i + 1];
    float2 a = h2p[i];                                // self-loop term
    for (int s = beg; s < end; ++s) {
        float2 v = h2p[csr[s]];
        a.x += v.x;
        a.y += v.y;
    }
    float di = dinv[i];
    out[i * 2 + 0] = di * a.x + b2[0];
    out[i * 2 + 1] = di * a.y + b2[1];
}

extern "C" void kernel_launch(void* const* d_in, const int* in_sizes, int n_in,
                              void* d_out, int out_size, void* d_ws, size_t ws_size,
                              hipStream_t stream) {
    const float* x  = (const float*)d_in[0];
    const int*   ei = (const int*)d_in[1];
    const float* W1 = (const float*)d_in[2];
    const float* b1 = (const float*)d_in[3];
    const float* W2 = (const float*)d_in[4];
    const float* b2 = (const float*)d_in[5];
    float* out = (float*)d_out;

    const int* src = ei;
    const int* dst = ei + N_EDGES;

    // workspace layout (4 B units; no aliasing)
    int*    wsi   = (int*)d_ws;
    int*    scnt  = wsi;                        // 51200 (32 x 1600)
    int*    bt    = wsi + 51200;                // 2048
    int*    bbase = wsi + 53248;                // 2048
    int*    scur  = wsi + 55296;                // 50176
    int*    off   = wsi + 105472;               // 100352 (N+1 used)
    float*  dinv  = (float*)(wsi + 205824);     // 100352
    int*    bin   = wsi + 306176;               // 1600000
    int*    csr   = wsi + 1906176;              // 1600000
    __half* h1p   = (__half*)(wsi + 3506176);   // 6.4M halves = 3.2M ints
    float2* h2p   = (float2*)(wsi + 6706176);   // 100000 float2

    dim3 B(256);
    k_zero   <<<(NSHARD * NBP + 255) / 256, B, 0, stream>>>(scnt);
    k_hist_s <<<GS, B, 0, stream>>>(dst, scnt);
    k_bsum   <<<8, B, 0, stream>>>(scnt, bt);
    k_bscan  <<<1, 1024, 0, stream>>>(bt, bbase, off);
    k_scur   <<<(NBUCK + 255) / 256, B, 0, stream>>>(bbase, scnt, scur);
    k_bin    <<<GS, B, 0, stream>>>(src, dst, scur, bin);
    k_csr    <<<NBUCK, B, 0, stream>>>(bin, bbase, off, dinv, csr);

    k_gemm1  <<<1024, B, 0, stream>>>(x, W1, dinv, h1p);
    k_gather1<<<N_NODES / 4, B, 0, stream>>>(h1p, off, csr, dinv, b1, W2, h2p);
    k_gather2<<<(N_NODES + 255) / 256, B, 0, stream>>>(h2p, off, csr, dinv, b2, out);
}

// Round 10
// 243.807 us; speedup vs baseline: 4.5558x; 1.2345x over previous
//
#include <hip/hip_runtime.h>
#include <hip/hip_fp16.h>

#define N_NODES 100000
#define N_EDGES 1600000
#define IN_F 128
#define HID 64
#define NBUCK 1563          // ceil(100000 / 64), 64 nodes per bucket
#define NBP 1600            // padded bucket stride
#define GS 512              // grid-stride blocks for hist_g / bin (mappings MUST match)

// ---------------- per-block bucket histogram -> gcnt[g][b], plain stores ----------------
__global__ __launch_bounds__(256) void k_hist_g(const int* __restrict__ dst,
                                                int* __restrict__ gcnt) {
    __shared__ int h[NBP];
    for (int t = threadIdx.x; t < NBP; t += 256) h[t] = 0;
    __syncthreads();
    const int g = blockIdx.x;
    for (int e = g * 256 + threadIdx.x; e < N_EDGES; e += GS * 256)
        atomicAdd(&h[dst[e] >> 6], 1);           // LDS only
    __syncthreads();
    int* row = gcnt + g * NBP;
    for (int t = threadIdx.x; t < NBP; t += 256) row[t] = h[t];   // coalesced, no atomics
}

// ---------------- per-bucket scan over blocks in XCD-grouped rank order ----------------
// rank r -> block g = (r%64)*8 + r/64  (same-XCD blocks contiguous in bin layout)
__global__ __launch_bounds__(512) void k_gbase(const int* __restrict__ gcnt,
                                               int* __restrict__ pre,
                                               int* __restrict__ bt) {
    const int b = blockIdx.x;
    if (b >= NBUCK) { if (threadIdx.x == 0) bt[b] = 0; return; }
    __shared__ int s[512];
    const int t = threadIdx.x;
    const int g = ((t & 63) << 3) | (t >> 6);    // rank -> block
    int v = gcnt[g * NBP + b];
    s[t] = v;
    __syncthreads();
    for (int o = 1; o < 512; o <<= 1) {
        int tt = (t >= o) ? s[t - o] : 0;
        __syncthreads();
        s[t] += tt;
        __syncthreads();
    }
    pre[g * NBP + b] = s[t] - v;                 // exclusive prefix in rank order
    if (t == 511) bt[b] = s[511];
}

// ---------------- single-block exclusive scan over 2048 bucket totals (proven) ----------
__global__ __launch_bounds__(1024) void k_bscan(const int* __restrict__ bt,
                                                int* __restrict__ bbase,
                                                int* __restrict__ off) {
    __shared__ int s[1024];
    const int t = threadIdx.x;
    int v0 = bt[2 * t], v1 = bt[2 * t + 1];
    int p = v0 + v1;
    s[t] = p;
    __syncthreads();
    for (int o = 1; o < 1024; o <<= 1) {
        int tt = (t >= o) ? s[t - o] : 0;
        __syncthreads();
        s[t] += tt;
        __syncthreads();
    }
    int base = s[t] - p;
    bbase[2 * t] = base;
    bbase[2 * t + 1] = base + v0;
    if (t == 0) off[N_NODES] = N_EDGES;     // CSR sentinel
}

// ---------------- bin: deterministic slots via LDS cursors (ZERO global atomics) ----------
__global__ __launch_bounds__(256) void k_bin(const int* __restrict__ src,
                                             const int* __restrict__ dst,
                                             const int* __restrict__ bbase,
                                             const int* __restrict__ pre,
                                             int* __restrict__ bin) {
    __shared__ int cur[NBP];
    const int g = blockIdx.x;
    const int* prow = pre + g * NBP;
    for (int t = threadIdx.x; t < NBP; t += 256)
        cur[t] = (t < NBUCK) ? (bbase[t] + prow[t]) : 0;
    __syncthreads();
    for (int e = g * 256 + threadIdx.x; e < N_EDGES; e += GS * 256) {
        int s = src[e], d = dst[e];
        int slot = atomicAdd(&cur[d >> 6], 1);   // LDS atomic only
        bin[slot] = ((d & 63) << 17) | s;        // src < 2^17, dst_local < 2^6
    }
}

// ---------------- per-bucket: histogram -> off/dinv, then reorder bin -> csr (proven) ----
__global__ __launch_bounds__(256) void k_csr(const int* __restrict__ bin,
                                             const int* __restrict__ bbase,
                                             int* __restrict__ off,
                                             float* __restrict__ dinv,
                                             int* __restrict__ csr) {
    __shared__ int cnt64[64];
    __shared__ int cur64[64];
    const int b = blockIdx.x;
    if (threadIdx.x < 64) cnt64[threadIdx.x] = 0;
    __syncthreads();
    const int beg = bbase[b], end = bbase[b + 1];
    for (int i = beg + threadIdx.x; i < end; i += 256)
        atomicAdd(&cnt64[(bin[i] >> 17) & 63], 1);
    __syncthreads();
    if (threadIdx.x == 0) {
        int run = beg;
        #pragma unroll
        for (int j = 0; j < 64; ++j) {
            cur64[j] = run;
            run += cnt64[j];
        }
    }
    __syncthreads();
    if (threadIdx.x < 64) {
        int node = b * 64 + threadIdx.x;
        if (node < N_NODES) {
            off[node] = cur64[threadIdx.x];
            dinv[node] = rsqrtf((float)(cnt64[threadIdx.x] + 1));  // +1 self-loop
        }
    }
    __syncthreads();
    for (int i = beg + threadIdx.x; i < end; i += 256) {
        int v = bin[i];
        int slot = atomicAdd(&cur64[(v >> 17) & 63], 1);
        csr[slot] = v & 0x1FFFF;
    }
}

// ---------------- layer 1 GEMM: h' = (x @ W1) * dinv -> fp16 (R8-proven) ----------------
__global__ __launch_bounds__(256) void k_gemm1(const float* __restrict__ x,
                                               const float* __restrict__ W1,
                                               const float* __restrict__ dinv,
                                               __half* __restrict__ h) {
    __shared__ float Ws[IN_F * HID];   // 32 KB
    __shared__ float xs[16][IN_F];     // 8 KB
    for (int t = threadIdx.x; t < IN_F * HID; t += 256) Ws[t] = W1[t];
    const int wave = threadIdx.x >> 6, lane = threadIdx.x & 63;
    const int ngroups = N_NODES / 16;  // 6250, exact
    for (int g = blockIdx.x; g < ngroups; g += gridDim.x) {
        __syncthreads();               // covers Ws load on first iter
        for (int t = threadIdx.x; t < 16 * IN_F; t += 256)
            xs[t >> 7][t & 127] = x[(size_t)(g * 16 + (t >> 7)) * IN_F + (t & 127)];
        __syncthreads();
        const int n0 = g * 16 + wave * 4;
        float a0 = 0.f, a1 = 0.f, a2 = 0.f, a3 = 0.f;
        #pragma unroll 8
        for (int k = 0; k < IN_F; ++k) {
            float wv = Ws[k * HID + lane];
            a0 += xs[wave * 4 + 0][k] * wv;
            a1 += xs[wave * 4 + 1][k] * wv;
            a2 += xs[wave * 4 + 2][k] * wv;
            a3 += xs[wave * 4 + 3][k] * wv;
        }
        h[(size_t)(n0 + 0) * HID + lane] = __float2half(a0 * dinv[n0 + 0]);
        h[(size_t)(n0 + 1) * HID + lane] = __float2half(a1 * dinv[n0 + 1]);
        h[(size_t)(n0 + 2) * HID + lane] = __float2half(a2 * dinv[n0 + 2]);
        h[(size_t)(n0 + 3) * HID + lane] = __float2half(a3 * dinv[n0 + 3]);
    }
}

// ---------------- layer 1 gather + ReLU + GEMM2 fused; 8 loads in flight (R9-proven) ------
__global__ __launch_bounds__(256) void k_gather1(const __half* __restrict__ h1,
                                                 const int* __restrict__ off,
                                                 const int* __restrict__ csr,
                                                 const float* __restrict__ dinv,
                                                 const float* __restrict__ b1,
                                                 const float* __restrict__ W2,
                                                 float2* __restrict__ h2p) {
    const int wave = threadIdx.x >> 6, lane = threadIdx.x & 63;
    const int d = blockIdx.x * 4 + wave;   // grid = 25000 blocks, exact
    const int beg = off[d], end = off[d + 1];
    float acc = __half2float(h1[(size_t)d * HID + lane]);   // self-loop term
    for (int base = beg; base < end; base += 64) {
        const int cnt = min(64, end - base);
        int sidx = (lane < cnt) ? csr[base + lane] : 0;     // OOB lanes -> row 0 (safe)
        for (int j = 0; j < cnt; j += 8) {
            float v[8];
            #pragma unroll
            for (int u = 0; u < 8; ++u) {                   // 8 independent loads in flight
                int jj = j + u;
                int s = __shfl(sidx, jj & 63, 64);
                float t = __half2float(h1[(size_t)s * HID + lane]);
                v[u] = (jj < cnt) ? t : 0.f;
            }
            #pragma unroll
            for (int u = 0; u < 8; ++u) acc += v[u];
        }
    }
    float y = dinv[d] * acc + b1[lane];
    y = y > 0.f ? y : 0.f;
    float c0 = y * W2[lane * 2 + 0];
    float c1 = y * W2[lane * 2 + 1];
    #pragma unroll
    for (int o = 32; o > 0; o >>= 1) {
        c0 += __shfl_xor(c0, o, 64);
        c1 += __shfl_xor(c1, o, 64);
    }
    if (lane == 0) {
        float di = dinv[d];
        h2p[d] = make_float2(c0 * di, c1 * di);
    }
}

// ---------------- layer 2 gather + finalize (R2-proven) ----------------
__global__ __launch_bounds__(256) void k_gather2(const float2* __restrict__ h2p,
                                                 const int* __restrict__ off,
                                                 const int* __restrict__ csr,
                                                 const float* __restrict__ dinv,
                                                 const float* __restrict__ b2,
                                                 float* __restrict__ out) {
    int i = blockIdx.x * 256 + threadIdx.x;
    if (i >= N_NODES) return;
    int beg = off[i], end = off[i + 1];
    float2 a = h2p[i];                                // self-loop term
    for (int s = beg; s < end; ++s) {
        float2 v = h2p[csr[s]];
        a.x += v.x;
        a.y += v.y;
    }
    float di = dinv[i];
    out[i * 2 + 0] = di * a.x + b2[0];
    out[i * 2 + 1] = di * a.y + b2[1];
}

extern "C" void kernel_launch(void* const* d_in, const int* in_sizes, int n_in,
                              void* d_out, int out_size, void* d_ws, size_t ws_size,
                              hipStream_t stream) {
    const float* x  = (const float*)d_in[0];
    const int*   ei = (const int*)d_in[1];
    const float* W1 = (const float*)d_in[2];
    const float* b1 = (const float*)d_in[3];
    const float* W2 = (const float*)d_in[4];
    const float* b2 = (const float*)d_in[5];
    float* out = (float*)d_out;

    const int* src = ei;
    const int* dst = ei + N_EDGES;

    // workspace layout (4 B units; no aliasing; ~33.8 MB)
    int*    wsi   = (int*)d_ws;
    int*    gcnt  = wsi;                        // 819200 (512 x 1600)
    int*    pre   = wsi + 819200;               // 819200
    int*    bt    = wsi + 1638400;              // 2048
    int*    bbase = wsi + 1640448;              // 2048
    int*    off   = wsi + 1642496;              // 100352 (N+1 used)
    float*  dinv  = (float*)(wsi + 1742848);    // 100352
    int*    bin   = wsi + 1843200;              // 1600000
    int*    csr   = wsi + 3443200;              // 1600000
    __half* h1p   = (__half*)(wsi + 5043200);   // 6.4M halves = 3.2M ints
    float2* h2p   = (float2*)(wsi + 8243200);   // 100000 float2

    dim3 B(256);
    k_hist_g <<<GS, B, 0, stream>>>(dst, gcnt);
    k_gbase  <<<2048, 512, 0, stream>>>(gcnt, pre, bt);
    k_bscan  <<<1, 1024, 0, stream>>>(bt, bbase, off);
    k_bin    <<<GS, B, 0, stream>>>(src, dst, bbase, pre, bin);
    k_csr    <<<NBUCK, B, 0, stream>>>(bin, bbase, off, dinv, csr);

    k_gemm1  <<<1024, B, 0, stream>>>(x, W1, dinv, h1p);
    k_gather1<<<N_NODES / 4, B, 0, stream>>>(h1p, off, csr, dinv, b1, W2, h2p);
    k_gather2<<<(N_NODES + 255) / 256, B, 0, stream>>>(h2p, off, csr, dinv, b2, out);
}

// Round 11
// 210.821 us; speedup vs baseline: 5.2686x; 1.1565x over previous
//
#include <hip/hip_runtime.h>
#include <hip/hip_fp16.h>

#define N_NODES 100000
#define N_EDGES 1600000
#define IN_F 128
#define HID 64
#define NBUCK 1563          // ceil(100000 / 64), 64 nodes per bucket
#define NBP 1600            // padded bucket stride
#define GS 512              // grid-stride blocks for hist_g / bin (mappings MUST match)

typedef _Float16 half8 __attribute__((ext_vector_type(8)));
typedef float f32x4 __attribute__((ext_vector_type(4)));

// ---------------- per-block bucket histogram -> gcnt[g][b], plain stores (R10-proven) -----
__global__ __launch_bounds__(256) void k_hist_g(const int* __restrict__ dst,
                                                int* __restrict__ gcnt) {
    __shared__ int h[NBP];
    for (int t = threadIdx.x; t < NBP; t += 256) h[t] = 0;
    __syncthreads();
    const int g = blockIdx.x;
    for (int e = g * 256 + threadIdx.x; e < N_EDGES; e += GS * 256)
        atomicAdd(&h[dst[e] >> 6], 1);           // LDS only
    __syncthreads();
    int* row = gcnt + g * NBP;
    for (int t = threadIdx.x; t < NBP; t += 256) row[t] = h[t];   // coalesced, no atomics
}

// ---------------- per-bucket scan over blocks in XCD-grouped rank order (R10-proven) ------
__global__ __launch_bounds__(512) void k_gbase(const int* __restrict__ gcnt,
                                               int* __restrict__ pre,
                                               int* __restrict__ bt) {
    const int b = blockIdx.x;
    if (b >= NBUCK) { if (threadIdx.x == 0) bt[b] = 0; return; }
    __shared__ int s[512];
    const int t = threadIdx.x;
    const int g = ((t & 63) << 3) | (t >> 6);    // rank -> block
    int v = gcnt[g * NBP + b];
    s[t] = v;
    __syncthreads();
    for (int o = 1; o < 512; o <<= 1) {
        int tt = (t >= o) ? s[t - o] : 0;
        __syncthreads();
        s[t] += tt;
        __syncthreads();
    }
    pre[g * NBP + b] = s[t] - v;                 // exclusive prefix in rank order
    if (t == 511) bt[b] = s[511];
}

// ---------------- single-block exclusive scan over 2048 bucket totals (proven) ----------
__global__ __launch_bounds__(1024) void k_bscan(const int* __restrict__ bt,
                                                int* __restrict__ bbase,
                                                int* __restrict__ off) {
    __shared__ int s[1024];
    const int t = threadIdx.x;
    int v0 = bt[2 * t], v1 = bt[2 * t + 1];
    int p = v0 + v1;
    s[t] = p;
    __syncthreads();
    for (int o = 1; o < 1024; o <<= 1) {
        int tt = (t >= o) ? s[t - o] : 0;
        __syncthreads();
        s[t] += tt;
        __syncthreads();
    }
    int base = s[t] - p;
    bbase[2 * t] = base;
    bbase[2 * t + 1] = base + v0;
    if (t == 0) off[N_NODES] = N_EDGES;     // CSR sentinel
}

// ---------------- bin: deterministic slots via LDS cursors (R10-proven) ----------
__global__ __launch_bounds__(256) void k_bin(const int* __restrict__ src,
                                             const int* __restrict__ dst,
                                             const int* __restrict__ bbase,
                                             const int* __restrict__ pre,
                                             int* __restrict__ bin) {
    __shared__ int cur[NBP];
    const int g = blockIdx.x;
    const int* prow = pre + g * NBP;
    for (int t = threadIdx.x; t < NBP; t += 256)
        cur[t] = (t < NBUCK) ? (bbase[t] + prow[t]) : 0;
    __syncthreads();
    for (int e = g * 256 + threadIdx.x; e < N_EDGES; e += GS * 256) {
        int s = src[e], d = dst[e];
        int slot = atomicAdd(&cur[d >> 6], 1);   // LDS atomic only
        bin[slot] = ((d & 63) << 17) | s;        // src < 2^17, dst_local < 2^6
    }
}

// ---------------- per-bucket: histogram -> off/dinv, then reorder bin -> csr (proven) ----
__global__ __launch_bounds__(256) void k_csr(const int* __restrict__ bin,
                                             const int* __restrict__ bbase,
                                             int* __restrict__ off,
                                             float* __restrict__ dinv,
                                             int* __restrict__ csr) {
    __shared__ int cnt64[64];
    __shared__ int cur64[64];
    const int b = blockIdx.x;
    if (threadIdx.x < 64) cnt64[threadIdx.x] = 0;
    __syncthreads();
    const int beg = bbase[b], end = bbase[b + 1];
    for (int i = beg + threadIdx.x; i < end; i += 256)
        atomicAdd(&cnt64[(bin[i] >> 17) & 63], 1);
    __syncthreads();
    if (threadIdx.x == 0) {
        int run = beg;
        #pragma unroll
        for (int j = 0; j < 64; ++j) {
            cur64[j] = run;
            run += cnt64[j];
        }
    }
    __syncthreads();
    if (threadIdx.x < 64) {
        int node = b * 64 + threadIdx.x;
        if (node < N_NODES) {
            off[node] = cur64[threadIdx.x];
            dinv[node] = rsqrtf((float)(cnt64[threadIdx.x] + 1));  // +1 self-loop
        }
    }
    __syncthreads();
    for (int i = beg + threadIdx.x; i < end; i += 256) {
        int v = bin[i];
        int slot = atomicAdd(&cur64[(v >> 17) & 63], 1);
        csr[slot] = v & 0x1FFFF;
    }
}

// ---------------- layer 1 GEMM via MFMA: h' = fp16((x @ W1) * dinv) ----------------
// wave = 16-node M-tile; N=64 -> 4 B-tiles; K=128 -> 4 chunks; 16 mfma/group/wave.
// A loaded direct from global (fp32->fp16 in regs); B repacked once into frag-ordered LDS.
__global__ __launch_bounds__(256) void k_gemm1(const float* __restrict__ x,
                                               const float* __restrict__ W1,
                                               const float* __restrict__ dinv,
                                               __half* __restrict__ hout) {
    __shared__ _Float16 Wl[8192];      // 16 KB, frag-ordered: [(nt*4+kc)*64+lane][8]
    const int tid = threadIdx.x, wave = tid >> 6, lane = tid & 63;
    const int quad = lane >> 4, m = lane & 15;
    // repack W1 into B-fragment order (one-time)
    for (int it = 0; it < 16; ++it) {
        int p = it * 256 + tid;                 // 0..4095 half2-pairs
        int j2 = p & 3, ln = (p >> 2) & 63, kc = (p >> 8) & 3, nt = p >> 10;
        int k = kc * 32 + ((ln >> 4) << 3) + j2 * 2;
        int n = nt * 16 + (ln & 15);
        Wl[p * 2]     = (_Float16)W1[k * HID + n];
        Wl[p * 2 + 1] = (_Float16)W1[(k + 1) * HID + n];
    }
    __syncthreads();
    half8 bf[16];                               // B frags in VGPRs for whole kernel
    #pragma unroll
    for (int i = 0; i < 16; ++i) bf[i] = ((const half8*)Wl)[i * 64 + lane];

    const int ngroups = NBUCK;                  // 1563 groups of 64 nodes
    for (int g = blockIdx.x; g < ngroups; g += gridDim.x) {
        const int n0 = g * 64 + wave * 16;      // this wave's 16-node tile
        if (n0 >= N_NODES) continue;            // only last group's waves 2,3
        const float4* xrow = (const float4*)(x + (size_t)(n0 + m) * IN_F);
        f32x4 acc[4] = {{0.f,0.f,0.f,0.f},{0.f,0.f,0.f,0.f},
                        {0.f,0.f,0.f,0.f},{0.f,0.f,0.f,0.f}};
        #pragma unroll
        for (int kc = 0; kc < 4; ++kc) {
            float4 p0 = xrow[kc * 8 + quad * 2 + 0];   // A[m][kc*32+quad*8 .. +3]
            float4 p1 = xrow[kc * 8 + quad * 2 + 1];   // .. +4..+7
            half8 a;
            a[0] = (_Float16)p0.x; a[1] = (_Float16)p0.y;
            a[2] = (_Float16)p0.z; a[3] = (_Float16)p0.w;
            a[4] = (_Float16)p1.x; a[5] = (_Float16)p1.y;
            a[6] = (_Float16)p1.z; a[7] = (_Float16)p1.w;
            #pragma unroll
            for (int nt = 0; nt < 4; ++nt)
                acc[nt] = __builtin_amdgcn_mfma_f32_16x16x32_f16(a, bf[nt * 4 + kc], acc[nt], 0, 0, 0);
        }
        // epilogue: D[row=quad*4+r][col=lane&15] -> h[(n0+row)*64 + nt*16 + col]
        float di[4];
        #pragma unroll
        for (int r = 0; r < 4; ++r) di[r] = dinv[n0 + quad * 4 + r];
        _Float16* hp = (_Float16*)hout;
        #pragma unroll
        for (int nt = 0; nt < 4; ++nt)
            #pragma unroll
            for (int r = 0; r < 4; ++r)
                hp[(size_t)(n0 + quad * 4 + r) * HID + nt * 16 + m] =
                    (_Float16)(acc[nt][r] * di[r]);
    }
}

// ---------------- layer 1 gather + ReLU + GEMM2 fused; 8 loads in flight (R9-proven) ------
__global__ __launch_bounds__(256) void k_gather1(const __half* __restrict__ h1,
                                                 const int* __restrict__ off,
                                                 const int* __restrict__ csr,
                                                 const float* __restrict__ dinv,
                                                 const float* __restrict__ b1,
                                                 const float* __restrict__ W2,
                                                 float2* __restrict__ h2p) {
    const int wave = threadIdx.x >> 6, lane = threadIdx.x & 63;
    const int d = blockIdx.x * 4 + wave;   // grid = 25000 blocks, exact
    const int beg = off[d], end = off[d + 1];
    float acc = __half2float(h1[(size_t)d * HID + lane]);   // self-loop term
    for (int base = beg; base < end; base += 64) {
        const int cnt = min(64, end - base);
        int sidx = (lane < cnt) ? csr[base + lane] : 0;     // OOB lanes -> row 0 (safe)
        for (int j = 0; j < cnt; j += 8) {
            float v[8];
            #pragma unroll
            for (int u = 0; u < 8; ++u) {                   // 8 independent loads in flight
                int jj = j + u;
                int s = __shfl(sidx, jj & 63, 64);
                float t = __half2float(h1[(size_t)s * HID + lane]);
                v[u] = (jj < cnt) ? t : 0.f;
            }
            #pragma unroll
            for (int u = 0; u < 8; ++u) acc += v[u];
        }
    }
    float y = dinv[d] * acc + b1[lane];
    y = y > 0.f ? y : 0.f;
    float c0 = y * W2[lane * 2 + 0];
    float c1 = y * W2[lane * 2 + 1];
    #pragma unroll
    for (int o = 32; o > 0; o >>= 1) {
        c0 += __shfl_xor(c0, o, 64);
        c1 += __shfl_xor(c1, o, 64);
    }
    if (lane == 0) {
        float di = dinv[d];
        h2p[d] = make_float2(c0 * di, c1 * di);
    }
}

// ---------------- layer 2 gather + finalize (R2-proven) ----------------
__global__ __launch_bounds__(256) void k_gather2(const float2* __restrict__ h2p,
                                                 const int* __restrict__ off,
                                                 const int* __restrict__ csr,
                                                 const float* __restrict__ dinv,
                                                 const float* __restrict__ b2,
                                                 float* __restrict__ out) {
    int i = blockIdx.x * 256 + threadIdx.x;
    if (i >= N_NODES) return;
    int beg = off[i], end = off[i + 1];
    float2 a = h2p[i];                                // self-loop term
    for (int s = beg; s < end; ++s) {
        float2 v = h2p[csr[s]];
        a.x += v.x;
        a.y += v.y;
    }
    float di = dinv[i];
    out[i * 2 + 0] = di * a.x + b2[0];
    out[i * 2 + 1] = di * a.y + b2[1];
}

extern "C" void kernel_launch(void* const* d_in, const int* in_sizes, int n_in,
                              void* d_out, int out_size, void* d_ws, size_t ws_size,
                              hipStream_t stream) {
    const float* x  = (const float*)d_in[0];
    const int*   ei = (const int*)d_in[1];
    const float* W1 = (const float*)d_in[2];
    const float* b1 = (const float*)d_in[3];
    const float* W2 = (const float*)d_in[4];
    const float* b2 = (const float*)d_in[5];
    float* out = (float*)d_out;

    const int* src = ei;
    const int* dst = ei + N_EDGES;

    // workspace layout (4 B units; no aliasing; ~33.8 MB)
    int*    wsi   = (int*)d_ws;
    int*    gcnt  = wsi;                        // 819200 (512 x 1600)
    int*    pre   = wsi + 819200;               // 819200
    int*    bt    = wsi + 1638400;              // 2048
    int*    bbase = wsi + 1640448;              // 2048
    int*    off   = wsi + 1642496;              // 100352 (N+1 used)
    float*  dinv  = (float*)(wsi + 1742848);    // 100352
    int*    bin   = wsi + 1843200;              // 1600000
    int*    csr   = wsi + 3443200;              // 1600000
    __half* h1p   = (__half*)(wsi + 5043200);   // 6.4M halves = 3.2M ints
    float2* h2p   = (float2*)(wsi + 8243200);   // 100000 float2

    dim3 B(256);
    k_hist_g <<<GS, B, 0, stream>>>(dst, gcnt);
    k_gbase  <<<2048, 512, 0, stream>>>(gcnt, pre, bt);
    k_bscan  <<<1, 1024, 0, stream>>>(bt, bbase, off);
    k_bin    <<<GS, B, 0, stream>>>(src, dst, bbase, pre, bin);
    k_csr    <<<NBUCK, B, 0, stream>>>(bin, bbase, off, dinv, csr);

    k_gemm1  <<<512, B, 0, stream>>>(x, W1, dinv, h1p);
    k_gather1<<<N_NODES / 4, B, 0, stream>>>(h1p, off, csr, dinv, b1, W2, h2p);
    k_gather2<<<(N_NODES + 255) / 256, B, 0, stream>>>(h2p, off, csr, dinv, b2, out);
}

// Round 12
// 205.909 us; speedup vs baseline: 5.3943x; 1.0239x over previous
//
#include <hip/hip_runtime.h>
#include <hip/hip_fp16.h>

#define N_NODES 100000
#define N_EDGES 1600000
#define IN_F 128
#define HID 64
#define NBUCK 1563          // ceil(100000 / 64), 64 nodes per bucket
#define NBP 1600            // padded bucket stride
#define GS 512              // grid-stride blocks for hist_g / bin (mappings MUST match)

typedef _Float16 half8 __attribute__((ext_vector_type(8)));
typedef _Float16 half4v __attribute__((ext_vector_type(4)));
typedef float f32x4 __attribute__((ext_vector_type(4)));

// ---------------- per-block bucket histogram -> gcnt[g][b], plain stores (R10-proven) -----
__global__ __launch_bounds__(256) void k_hist_g(const int* __restrict__ dst,
                                                int* __restrict__ gcnt) {
    __shared__ int h[NBP];
    for (int t = threadIdx.x; t < NBP; t += 256) h[t] = 0;
    __syncthreads();
    const int g = blockIdx.x;
    for (int e = g * 256 + threadIdx.x; e < N_EDGES; e += GS * 256)
        atomicAdd(&h[dst[e] >> 6], 1);           // LDS only
    __syncthreads();
    int* row = gcnt + g * NBP;
    for (int t = threadIdx.x; t < NBP; t += 256) row[t] = h[t];   // coalesced, no atomics
}

// ---------------- per-bucket scan over blocks in XCD-grouped rank order (R10-proven) ------
__global__ __launch_bounds__(512) void k_gbase(const int* __restrict__ gcnt,
                                               int* __restrict__ pre,
                                               int* __restrict__ bt) {
    const int b = blockIdx.x;
    if (b >= NBUCK) { if (threadIdx.x == 0) bt[b] = 0; return; }
    __shared__ int s[512];
    const int t = threadIdx.x;
    const int g = ((t & 63) << 3) | (t >> 6);    // rank -> block
    int v = gcnt[g * NBP + b];
    s[t] = v;
    __syncthreads();
    for (int o = 1; o < 512; o <<= 1) {
        int tt = (t >= o) ? s[t - o] : 0;
        __syncthreads();
        s[t] += tt;
        __syncthreads();
    }
    pre[g * NBP + b] = s[t] - v;                 // exclusive prefix in rank order
    if (t == 511) bt[b] = s[511];
}

// ---------------- single-block exclusive scan over 2048 bucket totals (proven) ----------
__global__ __launch_bounds__(1024) void k_bscan(const int* __restrict__ bt,
                                                int* __restrict__ bbase,
                                                int* __restrict__ off) {
    __shared__ int s[1024];
    const int t = threadIdx.x;
    int v0 = bt[2 * t], v1 = bt[2 * t + 1];
    int p = v0 + v1;
    s[t] = p;
    __syncthreads();
    for (int o = 1; o < 1024; o <<= 1) {
        int tt = (t >= o) ? s[t - o] : 0;
        __syncthreads();
        s[t] += tt;
        __syncthreads();
    }
    int base = s[t] - p;
    bbase[2 * t] = base;
    bbase[2 * t + 1] = base + v0;
    if (t == 0) off[N_NODES] = N_EDGES;     // CSR sentinel
}

// ---------------- bin: deterministic slots via LDS cursors (R10-proven) ----------
__global__ __launch_bounds__(256) void k_bin(const int* __restrict__ src,
                                             const int* __restrict__ dst,
                                             const int* __restrict__ bbase,
                                             const int* __restrict__ pre,
                                             int* __restrict__ bin) {
    __shared__ int cur[NBP];
    const int g = blockIdx.x;
    const int* prow = pre + g * NBP;
    for (int t = threadIdx.x; t < NBP; t += 256)
        cur[t] = (t < NBUCK) ? (bbase[t] + prow[t]) : 0;
    __syncthreads();
    for (int e = g * 256 + threadIdx.x; e < N_EDGES; e += GS * 256) {
        int s = src[e], d = dst[e];
        int slot = atomicAdd(&cur[d >> 6], 1);   // LDS atomic only
        bin[slot] = ((d & 63) << 17) | s;        // src < 2^17, dst_local < 2^6
    }
}

// ---------------- per-bucket: histogram -> off/dinv, then reorder bin -> csr (proven) ----
__global__ __launch_bounds__(256) void k_csr(const int* __restrict__ bin,
                                             const int* __restrict__ bbase,
                                             int* __restrict__ off,
                                             float* __restrict__ dinv,
                                             int* __restrict__ csr) {
    __shared__ int cnt64[64];
    __shared__ int cur64[64];
    const int b = blockIdx.x;
    if (threadIdx.x < 64) cnt64[threadIdx.x] = 0;
    __syncthreads();
    const int beg = bbase[b], end = bbase[b + 1];
    for (int i = beg + threadIdx.x; i < end; i += 256)
        atomicAdd(&cnt64[(bin[i] >> 17) & 63], 1);
    __syncthreads();
    if (threadIdx.x == 0) {
        int run = beg;
        #pragma unroll
        for (int j = 0; j < 64; ++j) {
            cur64[j] = run;
            run += cnt64[j];
        }
    }
    __syncthreads();
    if (threadIdx.x < 64) {
        int node = b * 64 + threadIdx.x;
        if (node < N_NODES) {
            off[node] = cur64[threadIdx.x];
            dinv[node] = rsqrtf((float)(cnt64[threadIdx.x] + 1));  // +1 self-loop
        }
    }
    __syncthreads();
    for (int i = beg + threadIdx.x; i < end; i += 256) {
        int v = bin[i];
        int slot = atomicAdd(&cur64[(v >> 17) & 63], 1);
        csr[slot] = v & 0x1FFFF;
    }
}

// ---------------- layer 1 GEMM via MFMA: h' = fp16((x @ W1) * dinv) (R11-proven) ----------
__global__ __launch_bounds__(256) void k_gemm1(const float* __restrict__ x,
                                               const float* __restrict__ W1,
                                               const float* __restrict__ dinv,
                                               __half* __restrict__ hout) {
    __shared__ _Float16 Wl[8192];      // 16 KB, frag-ordered: [(nt*4+kc)*64+lane][8]
    const int tid = threadIdx.x, wave = tid >> 6, lane = tid & 63;
    const int quad = lane >> 4, m = lane & 15;
    // zero row at index N_NODES (padding target for k_gather1)
    if (blockIdx.x == 0 && tid < 32) ((int*)hout)[(size_t)N_NODES * 32 + tid] = 0;
    // repack W1 into B-fragment order (one-time)
    for (int it = 0; it < 16; ++it) {
        int p = it * 256 + tid;                 // 0..4095 half2-pairs
        int j2 = p & 3, ln = (p >> 2) & 63, kc = (p >> 8) & 3, nt = p >> 10;
        int k = kc * 32 + ((ln >> 4) << 3) + j2 * 2;
        int n = nt * 16 + (ln & 15);
        Wl[p * 2]     = (_Float16)W1[k * HID + n];
        Wl[p * 2 + 1] = (_Float16)W1[(k + 1) * HID + n];
    }
    __syncthreads();
    half8 bf[16];                               // B frags in VGPRs for whole kernel
    #pragma unroll
    for (int i = 0; i < 16; ++i) bf[i] = ((const half8*)Wl)[i * 64 + lane];

    const int ngroups = NBUCK;                  // 1563 groups of 64 nodes
    for (int g = blockIdx.x; g < ngroups; g += gridDim.x) {
        const int n0 = g * 64 + wave * 16;      // this wave's 16-node tile
        if (n0 >= N_NODES) continue;            // only last group's waves 2,3
        const float4* xrow = (const float4*)(x + (size_t)(n0 + m) * IN_F);
        f32x4 acc[4] = {{0.f,0.f,0.f,0.f},{0.f,0.f,0.f,0.f},
                        {0.f,0.f,0.f,0.f},{0.f,0.f,0.f,0.f}};
        #pragma unroll
        for (int kc = 0; kc < 4; ++kc) {
            float4 p0 = xrow[kc * 8 + quad * 2 + 0];   // A[m][kc*32+quad*8 .. +3]
            float4 p1 = xrow[kc * 8 + quad * 2 + 1];   // .. +4..+7
            half8 a;
            a[0] = (_Float16)p0.x; a[1] = (_Float16)p0.y;
            a[2] = (_Float16)p0.z; a[3] = (_Float16)p0.w;
            a[4] = (_Float16)p1.x; a[5] = (_Float16)p1.y;
            a[6] = (_Float16)p1.z; a[7] = (_Float16)p1.w;
            #pragma unroll
            for (int nt = 0; nt < 4; ++nt)
                acc[nt] = __builtin_amdgcn_mfma_f32_16x16x32_f16(a, bf[nt * 4 + kc], acc[nt], 0, 0, 0);
        }
        // epilogue: D[row=quad*4+r][col=lane&15] -> h[(n0+row)*64 + nt*16 + col]
        float di[4];
        #pragma unroll
        for (int r = 0; r < 4; ++r) di[r] = dinv[n0 + quad * 4 + r];
        _Float16* hp = (_Float16*)hout;
        #pragma unroll
        for (int nt = 0; nt < 4; ++nt)
            #pragma unroll
            for (int r = 0; r < 4; ++r)
                hp[(size_t)(n0 + quad * 4 + r) * HID + nt * 16 + m] =
                    (_Float16)(acc[nt][r] * di[r]);
    }
}

// ---------------- layer 1 gather + ReLU + GEMM2; 4 rows/load, zero-row padding ------------
// lane = grp(=lane>>4) x fl(=lane&15); lane covers features [4fl..4fl+3] (half4 loads).
// group g accumulates edges e with e%4==g; groups merged via shfl_xor(32,16).
__global__ __launch_bounds__(256) void k_gather1(const __half* __restrict__ h1,
                                                 const int* __restrict__ off,
                                                 const int* __restrict__ csr,
                                                 const float* __restrict__ dinv,
                                                 const float* __restrict__ b1,
                                                 const float* __restrict__ W2,
                                                 float2* __restrict__ h2p) {
    const int wave = threadIdx.x >> 6, lane = threadIdx.x & 63;
    const int grp = lane >> 4, fl = lane & 15;
    const int d = blockIdx.x * 4 + wave;   // grid = 25000 blocks, exact
    const int beg = off[d], end = off[d + 1];
    const half4v* hrows = (const half4v*)h1;        // row r @ hrows[r*16 + fl]
    float a0 = 0.f, a1 = 0.f, a2 = 0.f, a3 = 0.f;
    for (int base = beg; base < end; base += 64) {
        const int cnt = min(64, end - base);
        int sidx = (lane < cnt) ? csr[base + lane] : N_NODES;   // OOB -> zero row
        for (int j = 0; j < cnt; j += 16) {
            int ss[4];
            #pragma unroll
            for (int u = 0; u < 4; ++u)
                ss[u] = __shfl(sidx, (j + 4 * u + grp) & 63, 64);
            half4v v[4];
            #pragma unroll
            for (int u = 0; u < 4; ++u)                 // 4 x 512B loads in flight
                v[u] = hrows[(size_t)ss[u] * 16 + fl];
            #pragma unroll
            for (int u = 0; u < 4; ++u) {
                a0 += (float)v[u][0];
                a1 += (float)v[u][1];
                a2 += (float)v[u][2];
                a3 += (float)v[u][3];
            }
        }
    }
    // merge the 4 group-partial sums
    #pragma unroll
    for (int o = 32; o >= 16; o >>= 1) {
        a0 += __shfl_xor(a0, o, 64);
        a1 += __shfl_xor(a1, o, 64);
        a2 += __shfl_xor(a2, o, 64);
        a3 += __shfl_xor(a3, o, 64);
    }
    // self-loop term
    half4v sv = hrows[(size_t)d * 16 + fl];
    a0 += (float)sv[0]; a1 += (float)sv[1]; a2 += (float)sv[2]; a3 += (float)sv[3];
    const float di = dinv[d];
    float4 bb = ((const float4*)b1)[fl];
    float y0 = fmaxf(di * a0 + bb.x, 0.f);
    float y1 = fmaxf(di * a1 + bb.y, 0.f);
    float y2 = fmaxf(di * a2 + bb.z, 0.f);
    float y3 = fmaxf(di * a3 + bb.w, 0.f);
    float4 w01 = ((const float4*)W2)[2 * fl];       // rows 4fl,4fl+1 (c0,c1 pairs)
    float4 w23 = ((const float4*)W2)[2 * fl + 1];   // rows 4fl+2,4fl+3
    float c0 = y0 * w01.x + y1 * w01.z + y2 * w23.x + y3 * w23.z;
    float c1 = y0 * w01.y + y1 * w01.w + y2 * w23.y + y3 * w23.w;
    #pragma unroll
    for (int o = 8; o > 0; o >>= 1) {               // reduce over fl bits only
        c0 += __shfl_xor(c0, o, 64);
        c1 += __shfl_xor(c1, o, 64);
    }
    if (lane == 0) h2p[d] = make_float2(c0 * di, c1 * di);
}

// ---------------- layer 2 gather + finalize (R2-proven) ----------------
__global__ __launch_bounds__(256) void k_gather2(const float2* __restrict__ h2p,
                                                 const int* __restrict__ off,
                                                 const int* __restrict__ csr,
                                                 const float* __restrict__ dinv,
                                                 const float* __restrict__ b2,
                                                 float* __restrict__ out) {
    int i = blockIdx.x * 256 + threadIdx.x;
    if (i >= N_NODES) return;
    int beg = off[i], end = off[i + 1];
    float2 a = h2p[i];                                // self-loop term
    for (int s = beg; s < end; ++s) {
        float2 v = h2p[csr[s]];
        a.x += v.x;
        a.y += v.y;
    }
    float di = dinv[i];
    out[i * 2 + 0] = di * a.x + b2[0];
    out[i * 2 + 1] = di * a.y + b2[1];
}

extern "C" void kernel_launch(void* const* d_in, const int* in_sizes, int n_in,
                              void* d_out, int out_size, void* d_ws, size_t ws_size,
                              hipStream_t stream) {
    const float* x  = (const float*)d_in[0];
    const int*   ei = (const int*)d_in[1];
    const float* W1 = (const float*)d_in[2];
    const float* b1 = (const float*)d_in[3];
    const float* W2 = (const float*)d_in[4];
    const float* b2 = (const float*)d_in[5];
    float* out = (float*)d_out;

    const int* src = ei;
    const int* dst = ei + N_EDGES;

    // workspace layout (4 B units; no aliasing; ~33.8 MB)
    int*    wsi   = (int*)d_ws;
    int*    gcnt  = wsi;                        // 819200 (512 x 1600)
    int*    pre   = wsi + 819200;               // 819200
    int*    bt    = wsi + 1638400;              // 2048
    int*    bbase = wsi + 1640448;              // 2048
    int*    off   = wsi + 1642496;              // 100352 (N+1 used)
    float*  dinv  = (float*)(wsi + 1742848);    // 100352
    int*    bin   = wsi + 1843200;              // 1600000
    int*    csr   = wsi + 3443200;              // 1600000
    __half* h1p   = (__half*)(wsi + 5043200);   // 100001 rows x 128B (incl. zero row)
    float2* h2p   = (float2*)(wsi + 8243264);   // 100000 float2

    dim3 B(256);
    k_hist_g <<<GS, B, 0, stream>>>(dst, gcnt);
    k_gbase  <<<2048, 512, 0, stream>>>(gcnt, pre, bt);
    k_bscan  <<<1, 1024, 0, stream>>>(bt, bbase, off);
    k_bin    <<<GS, B, 0, stream>>>(src, dst, bbase, pre, bin);
    k_csr    <<<NBUCK, B, 0, stream>>>(bin, bbase, off, dinv, csr);

    k_gemm1  <<<512, B, 0, stream>>>(x, W1, dinv, h1p);
    k_gather1<<<N_NODES / 4, B, 0, stream>>>(h1p, off, csr, dinv, b1, W2, h2p);
    k_gather2<<<(N_NODES + 255) / 256, B, 0, stream>>>(h2p, off, csr, dinv, b2, out);
}

// Round 13
// 191.204 us; speedup vs baseline: 5.8091x; 1.0769x over previous
//
#include <hip/hip_runtime.h>
#include <hip/hip_fp16.h>

#define N_NODES 100000
#define N_EDGES 1600000
#define IN_F 128
#define HID 64
#define NBUCK 1563          // ceil(100000 / 64), 64 nodes per bucket
#define NBP 1600            // padded bucket stride
#define GS 512              // grid-stride blocks for hist_g / bin (mappings MUST match)

typedef _Float16 half8 __attribute__((ext_vector_type(8)));
typedef _Float16 half4v __attribute__((ext_vector_type(4)));
typedef _Float16 half2v __attribute__((ext_vector_type(2)));
typedef float f32x4 __attribute__((ext_vector_type(4)));

// ---------------- per-block bucket histogram -> u16 gcnt[g][b] (int4 edge loads) ----------
__global__ __launch_bounds__(256) void k_hist_g(const int* __restrict__ dst,
                                                unsigned short* __restrict__ gcnt) {
    __shared__ int h[NBP];
    for (int t = threadIdx.x; t < NBP; t += 256) h[t] = 0;
    __syncthreads();
    const int g = blockIdx.x;
    const int NQ = N_EDGES / 4;                  // 400000, exact
    const int4* dst4 = (const int4*)dst;
    for (int q = g * 256 + threadIdx.x; q < NQ; q += GS * 256) {
        int4 d4 = dst4[q];
        atomicAdd(&h[d4.x >> 6], 1);
        atomicAdd(&h[d4.y >> 6], 1);
        atomicAdd(&h[d4.z >> 6], 1);
        atomicAdd(&h[d4.w >> 6], 1);
    }
    __syncthreads();
    unsigned int* row = (unsigned int*)(gcnt + g * NBP);
    for (int t = threadIdx.x; t < NBP / 2; t += 256)
        row[t] = (unsigned)h[2 * t] | ((unsigned)h[2 * t + 1] << 16);   // packed u16 pair
}

// ---------------- per-bucket scan over blocks; 8 buckets/block, uint4 (8xu16) lanes -------
// packed u16 lane arithmetic is carry-safe: bucket totals ~1200 << 32768
__global__ __launch_bounds__(512) void k_gbase(const unsigned short* __restrict__ gcnt,
                                               unsigned short* __restrict__ pre,
                                               int* __restrict__ bt) {
    __shared__ uint4 s[512];                     // 8 KB
    const int t = threadIdx.x;
    const int b0 = blockIdx.x * 8;               // grid 196 -> buckets 0..1567
    const int g = ((t & 63) << 3) | (t >> 6);    // rank -> block (XCD-grouped order)
    uint4 v = *(const uint4*)(gcnt + g * NBP + b0);
    uint4 run = v;
    s[t] = run;
    __syncthreads();
    for (int o = 1; o < 512; o <<= 1) {
        uint4 tt = {0u, 0u, 0u, 0u};
        if (t >= o) tt = s[t - o];
        __syncthreads();
        run.x += tt.x; run.y += tt.y; run.z += tt.z; run.w += tt.w;
        s[t] = run;
        __syncthreads();
    }
    uint4 ex = { run.x - v.x, run.y - v.y, run.z - v.z, run.w - v.w };  // exclusive, lane-safe
    *(uint4*)(pre + g * NBP + b0) = ex;
    if (t == 511) {
        bt[b0 + 0] = run.x & 0xFFFF; bt[b0 + 1] = run.x >> 16;
        bt[b0 + 2] = run.y & 0xFFFF; bt[b0 + 3] = run.y >> 16;
        bt[b0 + 4] = run.z & 0xFFFF; bt[b0 + 5] = run.z >> 16;
        bt[b0 + 6] = run.w & 0xFFFF; bt[b0 + 7] = run.w >> 16;
    }
}

// ---------------- single-block exclusive scan over bucket totals (proven core) ----------
__global__ __launch_bounds__(1024) void k_bscan(const int* __restrict__ bt,
                                                int* __restrict__ bbase,
                                                int* __restrict__ off) {
    __shared__ int s[1024];
    const int t = threadIdx.x;
    int v0 = (2 * t < 1568) ? bt[2 * t] : 0;         // only 1568 buckets written
    int v1 = (2 * t + 1 < 1568) ? bt[2 * t + 1] : 0;
    int p = v0 + v1;
    s[t] = p;
    __syncthreads();
    for (int o = 1; o < 1024; o <<= 1) {
        int tt = (t >= o) ? s[t - o] : 0;
        __syncthreads();
        s[t] += tt;
        __syncthreads();
    }
    int base = s[t] - p;
    bbase[2 * t] = base;
    bbase[2 * t + 1] = base + v0;
    if (t == 0) off[N_NODES] = N_EDGES;     // CSR sentinel
}

// ---------------- bin: deterministic slots via LDS cursors; int4 edge loads --------------
__global__ __launch_bounds__(256) void k_bin(const int* __restrict__ src,
                                             const int* __restrict__ dst,
                                             const int* __restrict__ bbase,
                                             const unsigned short* __restrict__ pre,
                                             int* __restrict__ bin) {
    __shared__ int cur[NBP];
    const int g = blockIdx.x;
    const unsigned short* prow = pre + g * NBP;
    for (int t = threadIdx.x; t < NBP; t += 256)
        cur[t] = (t < NBUCK) ? (bbase[t] + (int)prow[t]) : 0;
    __syncthreads();
    const int NQ = N_EDGES / 4;
    const int4* src4 = (const int4*)src;
    const int4* dst4 = (const int4*)dst;
    for (int q = g * 256 + threadIdx.x; q < NQ; q += GS * 256) {
        int4 s4 = src4[q];
        int4 d4 = dst4[q];
        int slot;
        slot = atomicAdd(&cur[d4.x >> 6], 1); bin[slot] = ((d4.x & 63) << 17) | s4.x;
        slot = atomicAdd(&cur[d4.y >> 6], 1); bin[slot] = ((d4.y & 63) << 17) | s4.y;
        slot = atomicAdd(&cur[d4.z >> 6], 1); bin[slot] = ((d4.z & 63) << 17) | s4.z;
        slot = atomicAdd(&cur[d4.w >> 6], 1); bin[slot] = ((d4.w & 63) << 17) | s4.w;
    }
}

// ---------------- per-bucket: histogram -> off/dinv, then reorder bin -> csr (proven) ----
__global__ __launch_bounds__(256) void k_csr(const int* __restrict__ bin,
                                             const int* __restrict__ bbase,
                                             int* __restrict__ off,
                                             float* __restrict__ dinv,
                                             int* __restrict__ csr) {
    __shared__ int cnt64[64];
    __shared__ int cur64[64];
    const int b = blockIdx.x;
    if (threadIdx.x < 64) cnt64[threadIdx.x] = 0;
    __syncthreads();
    const int beg = bbase[b], end = bbase[b + 1];
    for (int i = beg + threadIdx.x; i < end; i += 256)
        atomicAdd(&cnt64[(bin[i] >> 17) & 63], 1);
    __syncthreads();
    if (threadIdx.x == 0) {
        int run = beg;
        #pragma unroll
        for (int j = 0; j < 64; ++j) {
            cur64[j] = run;
            run += cnt64[j];
        }
    }
    __syncthreads();
    if (threadIdx.x < 64) {
        int node = b * 64 + threadIdx.x;
        if (node < N_NODES) {
            off[node] = cur64[threadIdx.x];
            dinv[node] = rsqrtf((float)(cnt64[threadIdx.x] + 1));  // +1 self-loop
        }
    }
    __syncthreads();
    for (int i = beg + threadIdx.x; i < end; i += 256) {
        int v = bin[i];
        int slot = atomicAdd(&cur64[(v >> 17) & 63], 1);
        csr[slot] = v & 0x1FFFF;
    }
}

// ---------------- layer 1 GEMM via MFMA: h' = fp16((x @ W1) * dinv) (R11-proven) ----------
__global__ __launch_bounds__(256) void k_gemm1(const float* __restrict__ x,
                                               const float* __restrict__ W1,
                                               const float* __restrict__ dinv,
                                               __half* __restrict__ hout) {
    __shared__ _Float16 Wl[8192];      // 16 KB, frag-ordered: [(nt*4+kc)*64+lane][8]
    const int tid = threadIdx.x, wave = tid >> 6, lane = tid & 63;
    const int quad = lane >> 4, m = lane & 15;
    // zero row at index N_NODES (padding target for k_gather1)
    if (blockIdx.x == 0 && tid < 32) ((int*)hout)[(size_t)N_NODES * 32 + tid] = 0;
    // repack W1 into B-fragment order (one-time)
    for (int it = 0; it < 16; ++it) {
        int p = it * 256 + tid;                 // 0..4095 half2-pairs
        int j2 = p & 3, ln = (p >> 2) & 63, kc = (p >> 8) & 3, nt = p >> 10;
        int k = kc * 32 + ((ln >> 4) << 3) + j2 * 2;
        int n = nt * 16 + (ln & 15);
        Wl[p * 2]     = (_Float16)W1[k * HID + n];
        Wl[p * 2 + 1] = (_Float16)W1[(k + 1) * HID + n];
    }
    __syncthreads();
    half8 bf[16];                               // B frags in VGPRs for whole kernel
    #pragma unroll
    for (int i = 0; i < 16; ++i) bf[i] = ((const half8*)Wl)[i * 64 + lane];

    const int ngroups = NBUCK;                  // 1563 groups of 64 nodes
    for (int g = blockIdx.x; g < ngroups; g += gridDim.x) {
        const int n0 = g * 64 + wave * 16;      // this wave's 16-node tile
        if (n0 >= N_NODES) continue;            // only last group's waves 2,3
        const float4* xrow = (const float4*)(x + (size_t)(n0 + m) * IN_F);
        f32x4 acc[4] = {{0.f,0.f,0.f,0.f},{0.f,0.f,0.f,0.f},
                        {0.f,0.f,0.f,0.f},{0.f,0.f,0.f,0.f}};
        #pragma unroll
        for (int kc = 0; kc < 4; ++kc) {
            float4 p0 = xrow[kc * 8 + quad * 2 + 0];   // A[m][kc*32+quad*8 .. +3]
            float4 p1 = xrow[kc * 8 + quad * 2 + 1];   // .. +4..+7
            half8 a;
            a[0] = (_Float16)p0.x; a[1] = (_Float16)p0.y;
            a[2] = (_Float16)p0.z; a[3] = (_Float16)p0.w;
            a[4] = (_Float16)p1.x; a[5] = (_Float16)p1.y;
            a[6] = (_Float16)p1.z; a[7] = (_Float16)p1.w;
            #pragma unroll
            for (int nt = 0; nt < 4; ++nt)
                acc[nt] = __builtin_amdgcn_mfma_f32_16x16x32_f16(a, bf[nt * 4 + kc], acc[nt], 0, 0, 0);
        }
        // epilogue: D[row=quad*4+r][col=lane&15] -> h[(n0+row)*64 + nt*16 + col]
        float di[4];
        #pragma unroll
        for (int r = 0; r < 4; ++r) di[r] = dinv[n0 + quad * 4 + r];
        _Float16* hp = (_Float16*)hout;
        #pragma unroll
        for (int nt = 0; nt < 4; ++nt)
            #pragma unroll
            for (int r = 0; r < 4; ++r)
                hp[(size_t)(n0 + quad * 4 + r) * HID + nt * 16 + m] =
                    (_Float16)(acc[nt][r] * di[r]);
    }
}

// ---------------- layer 1 gather + ReLU + GEMM2; packed fp16 adds, 4-edge flush -----------
__global__ __launch_bounds__(256) void k_gather1(const __half* __restrict__ h1,
                                                 const int* __restrict__ off,
                                                 const int* __restrict__ csr,
                                                 const float* __restrict__ dinv,
                                                 const float* __restrict__ b1,
                                                 const float* __restrict__ W2,
                                                 float2* __restrict__ h2p) {
    const int wave = threadIdx.x >> 6, lane = threadIdx.x & 63;
    const int grp = lane >> 4, fl = lane & 15;
    const int d = blockIdx.x * 4 + wave;   // grid = 25001 blocks
    if (d > N_NODES) return;
    if (d == N_NODES) {                    // zero row for gather2's padding
        if (lane == 0) h2p[d] = make_float2(0.f, 0.f);
        return;
    }
    const int beg = off[d], end = off[d + 1];
    const half4v* hrows = (const half4v*)h1;        // row r @ hrows[r*16 + fl]
    float a0 = 0.f, a1 = 0.f, a2 = 0.f, a3 = 0.f;
    for (int base = beg; base < end; base += 64) {
        const int cnt = min(64, end - base);
        int sidx = (lane < cnt) ? csr[base + lane] : N_NODES;   // OOB -> zero row
        for (int j = 0; j < cnt; j += 16) {
            int ss[4];
            #pragma unroll
            for (int u = 0; u < 4; ++u)
                ss[u] = __shfl(sidx, (j + 4 * u + grp) & 63, 64);
            half4v v[4];
            #pragma unroll
            for (int u = 0; u < 4; ++u)                 // 4 x 512B loads in flight
                v[u] = hrows[(size_t)ss[u] * 16 + fl];
            half2v p0 = {(_Float16)0.f, (_Float16)0.f};
            half2v p1 = {(_Float16)0.f, (_Float16)0.f};
            #pragma unroll
            for (int u = 0; u < 4; ++u) {               // v_pk_add_f16, 2 feats/instr
                p0 += __builtin_shufflevector(v[u], v[u], 0, 1);
                p1 += __builtin_shufflevector(v[u], v[u], 2, 3);
            }
            a0 += (float)p0[0]; a1 += (float)p0[1];     // fp32 flush every 4 edges/lane
            a2 += (float)p1[0]; a3 += (float)p1[1];
        }
    }
    // merge the 4 group-partial sums
    #pragma unroll
    for (int o = 32; o >= 16; o >>= 1) {
        a0 += __shfl_xor(a0, o, 64);
        a1 += __shfl_xor(a1, o, 64);
        a2 += __shfl_xor(a2, o, 64);
        a3 += __shfl_xor(a3, o, 64);
    }
    // self-loop term
    half4v sv = hrows[(size_t)d * 16 + fl];
    a0 += (float)sv[0]; a1 += (float)sv[1]; a2 += (float)sv[2]; a3 += (float)sv[3];
    const float di = dinv[d];
    float4 bb = ((const float4*)b1)[fl];
    float y0 = fmaxf(di * a0 + bb.x, 0.f);
    float y1 = fmaxf(di * a1 + bb.y, 0.f);
    float y2 = fmaxf(di * a2 + bb.z, 0.f);
    float y3 = fmaxf(di * a3 + bb.w, 0.f);
    float4 w01 = ((const float4*)W2)[2 * fl];       // rows 4fl,4fl+1 (c0,c1 pairs)
    float4 w23 = ((const float4*)W2)[2 * fl + 1];   // rows 4fl+2,4fl+3
    float c0 = y0 * w01.x + y1 * w01.z + y2 * w23.x + y3 * w23.z;
    float c1 = y0 * w01.y + y1 * w01.w + y2 * w23.y + y3 * w23.w;
    #pragma unroll
    for (int o = 8; o > 0; o >>= 1) {               // reduce over fl bits only
        c0 += __shfl_xor(c0, o, 64);
        c1 += __shfl_xor(c1, o, 64);
    }
    if (lane == 0) h2p[d] = make_float2(c0 * di, c1 * di);
}

// ---------------- layer 2 gather + finalize; 4 loads in flight, zero-row padding ----------
__global__ __launch_bounds__(256) void k_gather2(const float2* __restrict__ h2p,
                                                 const int* __restrict__ off,
                                                 const int* __restrict__ csr,
                                                 const float* __restrict__ dinv,
                                                 const float* __restrict__ b2,
                                                 float* __restrict__ out) {
    int i = blockIdx.x * 256 + threadIdx.x;
    if (i >= N_NODES) return;
    int beg = off[i], end = off[i + 1];
    float2 a = h2p[i];                                // self-loop term
    for (int s = beg; s < end; s += 4) {
        int node[4];
        #pragma unroll
        for (int u = 0; u < 4; ++u) {
            int idx = s + u;
            int n = csr[min(idx, end - 1)];           // always in-bounds load
            node[u] = (idx < end) ? n : N_NODES;      // padded -> zero row
        }
        float2 v[4];
        #pragma unroll
        for (int u = 0; u < 4; ++u) v[u] = h2p[node[u]];   // 4 loads in flight
        #pragma unroll
        for (int u = 0; u < 4; ++u) { a.x += v[u].x; a.y += v[u].y; }
    }
    float di = dinv[i];
    float2 o2 = make_float2(di * a.x + b2[0], di * a.y + b2[1]);
    ((float2*)out)[i] = o2;
}

extern "C" void kernel_launch(void* const* d_in, const int* in_sizes, int n_in,
                              void* d_out, int out_size, void* d_ws, size_t ws_size,
                              hipStream_t stream) {
    const float* x  = (const float*)d_in[0];
    const int*   ei = (const int*)d_in[1];
    const float* W1 = (const float*)d_in[2];
    const float* b1 = (const float*)d_in[3];
    const float* W2 = (const float*)d_in[4];
    const float* b2 = (const float*)d_in[5];
    float* out = (float*)d_out;

    const int* src = ei;
    const int* dst = ei + N_EDGES;

    // workspace layout (int units; no aliasing; ~30.5 MB)
    int*            wsi   = (int*)d_ws;
    unsigned short* gcnt  = (unsigned short*)wsi;            // 512x1600 u16 = 409600 ints
    unsigned short* pre   = (unsigned short*)(wsi + 409600); // 409600 ints
    int*            bt    = wsi + 819200;                    // 2048
    int*            bbase = wsi + 821248;                    // 2048
    int*            off   = wsi + 823296;                    // 100352 (N+1 used)
    float*          dinv  = (float*)(wsi + 923648);          // 100352
    int*            bin   = wsi + 1024000;                   // 1600000
    int*            csr   = wsi + 2624000;                   // 1600000
    __half*         h1p   = (__half*)(wsi + 4224000);        // 100001 rows x 128 B
    float2*         h2p   = (float2*)(wsi + 7424064);        // 100001 float2

    dim3 B(256);
    k_hist_g <<<GS, B, 0, stream>>>(dst, gcnt);
    k_gbase  <<<196, 512, 0, stream>>>(gcnt, pre, bt);       // 196*8 = 1568 buckets
    k_bscan  <<<1, 1024, 0, stream>>>(bt, bbase, off);
    k_bin    <<<GS, B, 0, stream>>>(src, dst, bbase, pre, bin);
    k_csr    <<<NBUCK, B, 0, stream>>>(bin, bbase, off, dinv, csr);

    k_gemm1  <<<512, B, 0, stream>>>(x, W1, dinv, h1p);
    k_gather1<<<N_NODES / 4 + 1, B, 0, stream>>>(h1p, off, csr, dinv, b1, W2, h2p);
    k_gather2<<<(N_NODES + 255) / 256, B, 0, stream>>>(h2p, off, csr, dinv, b2, out);
}